// Round 1
// baseline (559.863 us; speedup 1.0000x reference)
//
#include <hip/hip_runtime.h>
#include <stdint.h>

#define B_ 4
#define T_ 2048
#define D_ 1024
#define H_ 16
#define HD_ 64
#define DFF_ 4096
#define M_ (B_ * T_)  // 8192

typedef __bf16 bf16x8 __attribute__((ext_vector_type(8)));
typedef float f32x4 __attribute__((ext_vector_type(4)));

__device__ __forceinline__ uint16_t f2bf(float f) {
  union { float f; uint32_t u; } v;
  v.f = f;
  uint32_t r = v.u + 0x7FFF + ((v.u >> 16) & 1);  // RNE
  return (uint16_t)(r >> 16);
}

#define GLD_LDS(gp, lp)                                                        \
  __builtin_amdgcn_global_load_lds(                                            \
      (const __attribute__((address_space(1))) void*)(gp),                     \
      (__attribute__((address_space(3))) void*)(lp), 16, 0, 0)

// ---------------- LayerNorm fp32 -> bf16 (used for LN2) ----------------
__global__ __launch_bounds__(256) void ln_bf16(const float* __restrict__ x,
                                               const float* __restrict__ gamma,
                                               const float* __restrict__ beta,
                                               uint16_t* __restrict__ out) {
  __shared__ float red[4];
  const int tid = threadIdx.x;
  const size_t row = blockIdx.x;
  const float4 v = ((const float4*)(x + row * D_))[tid];
  float s = v.x + v.y + v.z + v.w;
#pragma unroll
  for (int off = 32; off >= 1; off >>= 1) s += __shfl_xor(s, off, 64);
  if ((tid & 63) == 0) red[tid >> 6] = s;
  __syncthreads();
  const float mean = (red[0] + red[1] + red[2] + red[3]) * (1.0f / D_);
  const float d0 = v.x - mean, d1 = v.y - mean, d2 = v.z - mean, d3 = v.w - mean;
  float ss = d0 * d0 + d1 * d1 + d2 * d2 + d3 * d3;
#pragma unroll
  for (int off = 32; off >= 1; off >>= 1) ss += __shfl_xor(ss, off, 64);
  __syncthreads();
  if ((tid & 63) == 0) red[tid >> 6] = ss;
  __syncthreads();
  const float var = (red[0] + red[1] + red[2] + red[3]) * (1.0f / D_);
  const float rstd = rsqrtf(var + 1e-5f);
  const float4 g = ((const float4*)gamma)[tid];
  const float4 b = ((const float4*)beta)[tid];
  ushort4 o;
  o.x = f2bf(d0 * rstd * g.x + b.x);
  o.y = f2bf(d1 * rstd * g.y + b.y);
  o.z = f2bf(d2 * rstd * g.z + b.z);
  o.w = f2bf(d3 * rstd * g.w + b.w);
  ((ushort4*)(out + row * D_))[tid] = o;
}

// ---- fused: LN1 (pid<8192) + weight prep (Wo/W1/W2 transposes + qkv rearrange) ----
__global__ __launch_bounds__(256) void prep_ln(
    const float* __restrict__ x, const float* __restrict__ g1,
    const float* __restrict__ be1, uint16_t* __restrict__ hbuf,
    const float* __restrict__ Wq, const float* __restrict__ Wk,
    const float* __restrict__ Wv, const float* __restrict__ Wo,
    const float* __restrict__ W1, const float* __restrict__ W2,
    uint16_t* __restrict__ wqkvt, uint16_t* __restrict__ wot,
    uint16_t* __restrict__ w1t, uint16_t* __restrict__ w2t) {
  const int pid = blockIdx.x;
  const int tid = threadIdx.x;

  if (pid < 8192) {  // LN1 row
    __shared__ float red[4];
    const size_t row = pid;
    const float4 v = ((const float4*)(x + row * D_))[tid];
    float s = v.x + v.y + v.z + v.w;
#pragma unroll
    for (int off = 32; off >= 1; off >>= 1) s += __shfl_xor(s, off, 64);
    if ((tid & 63) == 0) red[tid >> 6] = s;
    __syncthreads();
    const float mean = (red[0] + red[1] + red[2] + red[3]) * (1.0f / D_);
    const float d0 = v.x - mean, d1 = v.y - mean, d2 = v.z - mean, d3 = v.w - mean;
    float ss = d0 * d0 + d1 * d1 + d2 * d2 + d3 * d3;
#pragma unroll
    for (int off = 32; off >= 1; off >>= 1) ss += __shfl_xor(ss, off, 64);
    __syncthreads();
    if ((tid & 63) == 0) red[tid >> 6] = ss;
    __syncthreads();
    const float var = (red[0] + red[1] + red[2] + red[3]) * (1.0f / D_);
    const float rstd = rsqrtf(var + 1e-5f);
    const float4 g = ((const float4*)g1)[tid];
    const float4 b = ((const float4*)be1)[tid];
    ushort4 o;
    o.x = f2bf(d0 * rstd * g.x + b.x);
    o.y = f2bf(d1 * rstd * g.y + b.y);
    o.z = f2bf(d2 * rstd * g.z + b.z);
    o.w = f2bf(d3 * rstd * g.w + b.w);
    ((ushort4*)(hbuf + row * D_))[tid] = o;
    return;
  }

  __shared__ float tile[32][33];
  const int tx = tid & 31, ty = tid >> 5;
  const int q = pid - 8192;

  if (q >= 9216) {  // qkv rearrange [H][D][HD] -> [which*1024+h*64+e][D]
    const int p = q - 9216;
    const int bx = p & 1, by = (p >> 1) & 31, z = p >> 6;
    const int which = z >> 4, hh = z & 15;
    const float* W = (which == 0) ? Wq : ((which == 1) ? Wk : Wv);
    const float* in = W + (size_t)hh * D_ * HD_;
    const int e0 = bx * 32, d0 = by * 32;
#pragma unroll
    for (int i = 0; i < 32; i += 8)
      tile[ty + i][tx] = in[(size_t)(d0 + ty + i) * HD_ + e0 + tx];
    __syncthreads();
#pragma unroll
    for (int i = 0; i < 32; i += 8)
      wqkvt[((size_t)(which * 1024 + hh * 64) + e0 + ty + i) * D_ + d0 + tx] =
          f2bf(tile[tx][ty + i]);
    return;
  }

  const float* in;
  uint16_t* out;
  int R, C, bx, by;
  if (q < 1024) {
    in = Wo; out = wot; R = 1024; C = 1024; bx = q & 31; by = q >> 5;
  } else if (q < 5120) {
    const int p = q - 1024;
    in = W1; out = w1t; R = 1024; C = 4096; bx = p & 127; by = p >> 7;
  } else {
    const int p = q - 5120;
    in = W2; out = w2t; R = 4096; C = 1024; bx = p & 31; by = p >> 5;
  }
  const int c0 = bx * 32, r0 = by * 32;
#pragma unroll
  for (int i = 0; i < 32; i += 8)
    tile[ty + i][tx] = in[(size_t)(r0 + ty + i) * C + c0 + tx];
  __syncthreads();
#pragma unroll
  for (int i = 0; i < 32; i += 8)
    out[(size_t)(c0 + ty + i) * R + r0 + tx] = f2bf(tile[tx][ty + i]);
}

// ---------------- bf16 MFMA GEMM (2-phase 128-tile; kept for N=1024 shapes) ----
// flags: 1 = relu, 2 = bf16 output
template <int BN>
__global__ __launch_bounds__(256) void gemm_bf16(const uint16_t* __restrict__ A,
                                                 const uint16_t* __restrict__ Bt,
                                                 void* __restrict__ C,
                                                 const float* __restrict__ bias,
                                                 const float* __restrict__ resid,
                                                 int M, int N, int K, int lda,
                                                 int ldb, int flags) {
  constexpr int NJ = BN / 32;  // j-frags per wave
  __shared__ __align__(16) uint16_t As[128 * 64];
  __shared__ __align__(16) uint16_t Bs[BN * 64];
  const int tid = threadIdx.x;
  const int lane = tid & 63, w = tid >> 6;
  const int quad = lane >> 4, lr = lane & 15;
  const int wr = w >> 1, wc = w & 1;

  const int n_tiles = N / BN;
  const int pid = blockIdx.x;
  const int grp = 16 * n_tiles;
  const int gid = pid / grp;
  const int rem = pid - gid * grp;
  const int nt = rem / 16;
  const int mt = gid * 16 + (rem - nt * 16);
  const int bn0 = nt * BN, bm0 = mt * 128;

  f32x4 acc[4][NJ];
#pragma unroll
  for (int i = 0; i < 4; i++)
#pragma unroll
    for (int j = 0; j < NJ; j++) acc[i][j] = f32x4{0.f, 0.f, 0.f, 0.f};

  const int s_row = lane >> 3, s_slot = lane & 7;

  for (int k0 = 0; k0 < K; k0 += 64) {
#pragma unroll
    for (int u = 0; u < 4; u++) {
      const int r = w * 32 + u * 8 + s_row;
      const int cg = s_slot ^ (r & 7);
      GLD_LDS(A + (size_t)(bm0 + r) * lda + k0 + cg * 8, As + (w * 32 + u * 8) * 64);
    }
#pragma unroll
    for (int u = 0; u < NJ; u++) {
      const int r = w * (BN / 4) + u * 8 + s_row;
      const int cg = s_slot ^ (r & 7);
      GLD_LDS(Bt + (size_t)(bn0 + r) * ldb + k0 + cg * 8,
              Bs + (w * (BN / 4) + u * 8) * 64);
    }
    __syncthreads();

#pragma unroll
    for (int ks = 0; ks < 2; ks++) {
      bf16x8 af[4], bfr[NJ];
#pragma unroll
      for (int i = 0; i < 4; i++) {
        const int m = wr * 64 + i * 16 + lr;
        const int slot = (ks * 4 + quad) ^ (m & 7);
        af[i] = *(const bf16x8*)(As + m * 64 + slot * 8);
      }
#pragma unroll
      for (int j = 0; j < NJ; j++) {
        const int n = wc * (BN / 2) + j * 16 + lr;
        const int slot = (ks * 4 + quad) ^ (n & 7);
        bfr[j] = *(const bf16x8*)(Bs + n * 64 + slot * 8);
      }
#pragma unroll
      for (int i = 0; i < 4; i++)
#pragma unroll
        for (int j = 0; j < NJ; j++)
          acc[i][j] =
              __builtin_amdgcn_mfma_f32_16x16x32_bf16(af[i], bfr[j], acc[i][j], 0, 0, 0);
    }
    __syncthreads();
  }

  const int base_m = bm0 + wr * 64 + quad * 4;
  const int base_n = bn0 + wc * (BN / 2) + lr;
#pragma unroll
  for (int i = 0; i < 4; i++) {
#pragma unroll
    for (int j = 0; j < NJ; j++) {
      const int col = base_n + j * 16;
      const float bv = bias ? bias[col] : 0.f;
#pragma unroll
      for (int r = 0; r < 4; r++) {
        const size_t row = base_m + i * 16 + r;
        float v = acc[i][j][r] + bv;
        if (resid) v += resid[row * N + col];
        if (flags & 1) v = fmaxf(v, 0.f);
        if (flags & 2)
          ((uint16_t*)C)[row * N + col] = f2bf(v);
        else
          ((float*)C)[row * N + col] = v;
      }
    }
  }
}

// ---------------- 256x256 8-phase bf16 MFMA GEMM (T2+T3+T4+T5) ----------------
// 512 threads = 8 waves (2M x 4N). BK=64, double-buffered 128 KiB LDS.
// Per K-tile: 4 phases (ks x m-half), 16 MFMA each under setprio(1).
// All 8 staging gld_lds for tile t+1 issued at phase 1 -> single vmcnt(0) at the
// tile boundary waits for loads issued ~3 phases (~1000 cy) earlier (no drain
// stall). Raw s_barrier (never __syncthreads) inside the loop.
// Same chunk-XOR LDS swizzle as gemm_bf16 (measured 0 bank conflicts).
// Requires M%256==0, N%256==0, K%64==0, grid=(M/256)*(N/256), grid%8==0.
#define STAGE8(buf, kt)                                                        \
  do {                                                                         \
    const int k0s = (kt) * 64;                                                 \
    _Pragma("unroll") for (int u = 0; u < 4; u++) {                            \
      const int r = w * 32 + u * 8 + s_row;                                    \
      const int cg = s_slot ^ (r & 7);                                         \
      GLD_LDS(A + (size_t)(bm0 + r) * lda + k0s + cg * 8,                      \
              &As[buf][(w * 32 + u * 8) * 64]);                                \
      GLD_LDS(Bt + (size_t)(bn0 + r) * ldb + k0s + cg * 8,                     \
              &Bs[buf][(w * 32 + u * 8) * 64]);                                \
    }                                                                          \
  } while (0)

#define RD_A8(dst, ibase, ks)                                                  \
  _Pragma("unroll") for (int i = 0; i < 4; i++) {                              \
    const int m = wr * 128 + ((ibase) + i) * 16 + lr;                          \
    const int slot = ((ks) * 4 + quad) ^ (m & 7);                              \
    dst[i] = *(const bf16x8*)(&As[c][m * 64 + slot * 8]);                      \
  }

#define RD_B8(dst, ks)                                                         \
  _Pragma("unroll") for (int j = 0; j < 4; j++) {                              \
    const int n = wc * 64 + j * 16 + lr;                                       \
    const int slot = ((ks) * 4 + quad) ^ (n & 7);                              \
    dst[j] = *(const bf16x8*)(&Bs[c][n * 64 + slot * 8]);                      \
  }

#define MFMA16(ibase, aarr)                                                    \
  do {                                                                         \
    __builtin_amdgcn_s_setprio(1);                                             \
    _Pragma("unroll") for (int i = 0; i < 4; i++)                              \
        _Pragma("unroll") for (int j = 0; j < 4; j++) acc[(ibase) + i][j] =    \
        __builtin_amdgcn_mfma_f32_16x16x32_bf16(aarr[i], bb[j],                \
                                                acc[(ibase) + i][j], 0, 0, 0); \
    __builtin_amdgcn_s_setprio(0);                                             \
  } while (0)

__global__ __launch_bounds__(512, 2) void gemm_8ph(
    const uint16_t* __restrict__ A, const uint16_t* __restrict__ Bt,
    void* __restrict__ C, const float* __restrict__ bias,
    const float* __restrict__ resid, int M, int N, int K, int lda, int ldb,
    int flags) {
  __shared__ __align__(16) uint16_t As[2][256 * 64];  // 64 KiB
  __shared__ __align__(16) uint16_t Bs[2][256 * 64];  // 64 KiB
  const int tid = threadIdx.x;
  const int lane = tid & 63, w = tid >> 6;
  const int quad = lane >> 4, lr = lane & 15;
  const int wr = w >> 2, wc = w & 3;  // 2 x 4 wave grid; per-wave out 128x64
  const int s_row = lane >> 3, s_slot = lane & 7;

  // bijective XCD swizzle (grid % 8 == 0), then n-fastest raster:
  // consecutive blocks on one XCD share the A m-panel -> L2 reuse.
  const int nwg = gridDim.x;
  const int cpx = nwg >> 3;
  const int pid0 = blockIdx.x;
  const int pid = (pid0 & 7) * cpx + (pid0 >> 3);
  const int n_tiles = N >> 8;
  const int mt = pid / n_tiles;
  const int nt = pid - mt * n_tiles;
  const int bm0 = mt * 256, bn0 = nt * 256;

  f32x4 acc[8][4];
#pragma unroll
  for (int i = 0; i < 8; i++)
#pragma unroll
    for (int j = 0; j < 4; j++) acc[i][j] = f32x4{0.f, 0.f, 0.f, 0.f};

  STAGE8(0, 0);
  asm volatile("s_waitcnt vmcnt(0)" ::: "memory");
  __builtin_amdgcn_s_barrier();

  const int NT = K >> 6;
  for (int t = 0; t < NT; ++t) {
    const int c = t & 1;
    bf16x8 a_lo[4], a_hi[4], bb[4];
    // ---- phase 1: ks=0, m-frags 0-3; issue next tile's staging ----
    RD_A8(a_lo, 0, 0);
    RD_B8(bb, 0);
    if (t + 1 < NT) STAGE8(c ^ 1, t + 1);
    __builtin_amdgcn_s_barrier();
    MFMA16(0, a_lo);
    __builtin_amdgcn_s_barrier();
    // ---- phase 2: ks=0, m-frags 4-7 (reuse bb) ----
    RD_A8(a_hi, 4, 0);
    __builtin_amdgcn_s_barrier();
    MFMA16(4, a_hi);
    __builtin_amdgcn_s_barrier();
    // ---- phase 3: ks=1, m-frags 0-3 ----
    RD_A8(a_lo, 0, 1);
    RD_B8(bb, 1);
    __builtin_amdgcn_s_barrier();
    MFMA16(0, a_lo);
    __builtin_amdgcn_s_barrier();
    // ---- phase 4: ks=1, m-frags 4-7; tile boundary wait ----
    RD_A8(a_hi, 4, 1);
    __builtin_amdgcn_s_barrier();
    MFMA16(4, a_hi);
    asm volatile("s_waitcnt vmcnt(0)" ::: "memory");
    __builtin_amdgcn_s_barrier();
  }

  const int base_m = bm0 + wr * 128 + quad * 4;
  const int base_n = bn0 + wc * 64 + lr;
#pragma unroll
  for (int i = 0; i < 8; i++) {
#pragma unroll
    for (int j = 0; j < 4; j++) {
      const int col = base_n + j * 16;
      const float bv = bias ? bias[col] : 0.f;
#pragma unroll
      for (int r = 0; r < 4; r++) {
        const size_t row = base_m + i * 16 + r;
        float v = acc[i][j][r] + bv;
        if (resid) v += resid[row * N + col];
        if (flags & 1) v = fmaxf(v, 0.f);
        if (flags & 2)
          ((uint16_t*)C)[row * N + col] = f2bf(v);
        else
          ((float*)C)[row * N + col] = v;
      }
    }
  }
}

// ---- V transpose: qkv V-region [B*T][3072] -> vtb [(b*H+h)*64+e][T] bf16 ----
__global__ __launch_bounds__(256) void v_transpose(const uint16_t* __restrict__ qkv,
                                                   uint16_t* __restrict__ vtb) {
  __shared__ __align__(16) uint16_t tile[64 * 72];  // [t-local][e]
  const int tid = threadIdx.x;
  const int t0 = blockIdx.x * 64;
  const int bh = blockIdx.y;
  const int b = bh >> 4, h = bh & 15;
  const uint16_t* src = qkv + (size_t)b * T_ * 3072 + 2048 + h * 64;
#pragma unroll
  for (int u = 0; u < 2; u++) {
    const int uu = tid + u * 256;
    const int r = uu >> 3, c = uu & 7;
    *(int4*)(tile + r * 72 + c * 8) =
        *(const int4*)(src + (size_t)(t0 + r) * 3072 + c * 8);
  }
  __syncthreads();
  uint16_t* dst = vtb + ((size_t)bh * 64) * T_ + t0;
#pragma unroll
  for (int u = 0; u < 2; u++) {
    const int uu = tid + u * 256;
    const int e = uu >> 3, c2 = uu & 7;
    union { uint16_t u16[8]; int4 v; } tmp;
#pragma unroll
    for (int jj = 0; jj < 8; jj++) tmp.u16[jj] = tile[(c2 * 8 + jj) * 72 + e];
    *(int4*)(dst + (size_t)e * T_ + c2 * 8) = tmp.v;
  }
}

// ---- per-stage compute for one q-tile (S^T MFMA + static-max softmax + PV) ----
__device__ __forceinline__ void attn_tile_compute(
    const uint16_t* __restrict__ Kb, const uint16_t* __restrict__ Vb,
    uint16_t* __restrict__ Ps, const bf16x8 (&aq)[2][2], f32x4 (&oacc)[2][4],
    float (&l_part)[2], int st, int q0, int w, int quad, int lr) {
  const int lr7 = lr & 7;
  const int row_min_w = q0 + w * 32;

  // S^T = K @ Q^T : frag rows = s (4 sf-frags), cols = m (2 i-frags)
  f32x4 sa[2][4];
#pragma unroll
  for (int i = 0; i < 2; i++)
#pragma unroll
    for (int sf = 0; sf < 4; sf++) sa[i][sf] = f32x4{0.f, 0.f, 0.f, 0.f};
#pragma unroll
  for (int ks = 0; ks < 2; ks++) {
    bf16x8 ak[4];
#pragma unroll
    for (int sf = 0; sf < 4; sf++) {
      const int slot = (ks * 4 + quad) ^ lr7;
      ak[sf] = *(const bf16x8*)(Kb + (sf * 16 + lr) * 64 + slot * 8);
    }
#pragma unroll
    for (int i = 0; i < 2; i++)
#pragma unroll
      for (int sf = 0; sf < 4; sf++)
        sa[i][sf] =
            __builtin_amdgcn_mfma_f32_16x16x32_bf16(ak[sf], aq[i][ks], sa[i][sf], 0, 0, 0);
  }

  // p = exp2(s*log2e/8 - 20*log2e); mask only on the diagonal stage
  const bool diag = (st * 64 + 63 > row_min_w);
  if (diag) {
#pragma unroll
    for (int i = 0; i < 2; i++) {
      const int mrow = q0 + w * 32 + i * 16 + lr;
#pragma unroll
      for (int sf = 0; sf < 4; sf++) {
        const int s0 = st * 64 + sf * 16 + quad * 4;
        float p[4];
#pragma unroll
        for (int r = 0; r < 4; r++) {
          float sv = sa[i][sf][r];
          if (s0 + r > mrow) sv = -1e30f;
          p[r] = exp2f(fmaf(sv, 0.18033688f, -28.8539008f));
          l_part[i] += p[r];
        }
        ushort4 pk;
        pk.x = f2bf(p[0]);
        pk.y = f2bf(p[1]);
        pk.z = f2bf(p[2]);
        pk.w = f2bf(p[3]);
        *(ushort4*)(Ps + (size_t)(w * 32 + i * 16 + lr) * 72 + sf * 16 + quad * 4) = pk;
      }
    }
  } else {
#pragma unroll
    for (int i = 0; i < 2; i++) {
#pragma unroll
      for (int sf = 0; sf < 4; sf++) {
        float p[4];
#pragma unroll
        for (int r = 0; r < 4; r++) {
          p[r] = exp2f(fmaf(sa[i][sf][r], 0.18033688f, -28.8539008f));
          l_part[i] += p[r];
        }
        ushort4 pk;
        pk.x = f2bf(p[0]);
        pk.y = f2bf(p[1]);
        pk.z = f2bf(p[2]);
        pk.w = f2bf(p[3]);
        *(ushort4*)(Ps + (size_t)(w * 32 + i * 16 + lr) * 72 + sf * 16 + quad * 4) = pk;
      }
    }
  }

  // O += P @ V (per-wave LDS region, same-wave write->read)
#pragma unroll
  for (int ks = 0; ks < 2; ks++) {
    bf16x8 ap[2], bv[4];
#pragma unroll
    for (int i = 0; i < 2; i++)
      ap[i] = *(const bf16x8*)(Ps + (size_t)(w * 32 + i * 16 + lr) * 72 + ks * 32 +
                               quad * 8);
#pragma unroll
    for (int j = 0; j < 4; j++) {
      const int slot = (ks * 4 + quad) ^ lr7;
      bv[j] = *(const bf16x8*)(Vb + (j * 16 + lr) * 64 + slot * 8);
    }
#pragma unroll
    for (int i = 0; i < 2; i++)
#pragma unroll
      for (int j = 0; j < 4; j++)
        oacc[i][j] =
            __builtin_amdgcn_mfma_f32_16x16x32_bf16(ap[i], bv[j], oacc[i][j], 0, 0, 0);
  }
}

// ---------------- MFMA flash attention: paired q-tiles + XCD-local K/V ----------
__global__ __launch_bounds__(256) void attn_mfma(const uint16_t* __restrict__ qkv,
                                                 const uint16_t* __restrict__ vtb,
                                                 uint16_t* __restrict__ ctx) {
  __shared__ __align__(16) uint16_t Ks[64 * 64];   // [s][d] swizzled chunks
  __shared__ __align__(16) uint16_t Vt[64 * 64];   // [d][s] swizzled chunks
  __shared__ __align__(16) uint16_t Ps[128 * 72];  // [m][s] plain, padded
  const int tid = threadIdx.x;
  const int lane = tid & 63, w = tid >> 6;
  const int quad = lane >> 4, lr = lane & 15;
  const int pid = blockIdx.x;
  const int bh = pid & 63;         // same XCD for all i of this (b,h)
  const int i_pair = pid >> 6;     // 0..7
  const int b = bh >> 4, h = bh & 15;
  const uint16_t* base = qkv + (size_t)b * T_ * 3072 + h * 64;
  const uint16_t* vbase = vtb + ((size_t)bh * 64) * T_;
  const int s_row = lane >> 3, s_slot = lane & 7;

  const int tqA = i_pair, tqB = 15 - i_pair;
  const int q0A = tqA * 128, q0B = tqB * 128;
  const int nstgA = 2 * tqA + 2, nstgB = 2 * tqB + 2;
  const int nstg = (nstgA > nstgB) ? nstgA : nstgB;

  bf16x8 aqA[2][2], aqB[2][2];
#pragma unroll
  for (int i = 0; i < 2; i++)
#pragma unroll
    for (int ks = 0; ks < 2; ks++) {
      aqA[i][ks] = *(const bf16x8*)(base + (size_t)(q0A + w * 32 + i * 16 + lr) * 3072 +
                                    ks * 32 + quad * 8);
      aqB[i][ks] = *(const bf16x8*)(base + (size_t)(q0B + w * 32 + i * 16 + lr) * 3072 +
                                    ks * 32 + quad * 8);
    }

  f32x4 oaccA[2][4], oaccB[2][4];
#pragma unroll
  for (int i = 0; i < 2; i++)
#pragma unroll
    for (int j = 0; j < 4; j++) {
      oaccA[i][j] = f32x4{0.f, 0.f, 0.f, 0.f};
      oaccB[i][j] = f32x4{0.f, 0.f, 0.f, 0.f};
    }
  float lA[2] = {0.f, 0.f}, lB[2] = {0.f, 0.f};

  const int row_maxA = q0A + w * 32 + 31;
  const int row_maxB = q0B + w * 32 + 31;

  for (int st = 0; st < nstg; st++) {
    __syncthreads();  // prior stage's LDS reads complete
#pragma unroll
    for (int u = 0; u < 2; u++) {
      const int r = w * 16 + u * 8 + s_row;
      const int cg = s_slot ^ (r & 7);
      GLD_LDS(base + 1024 + (size_t)(st * 64 + r) * 3072 + cg * 8,
              Ks + (w * 16 + u * 8) * 64);
      GLD_LDS(vbase + (size_t)r * T_ + st * 64 + cg * 8, Vt + (w * 16 + u * 8) * 64);
    }
    __syncthreads();

    if (st < nstgA && st * 64 <= row_maxA)
      attn_tile_compute(Ks, Vt, Ps, aqA, oaccA, lA, st, q0A, w, quad, lr);
    if (st < nstgB && st * 64 <= row_maxB)
      attn_tile_compute(Ks, Vt, Ps, aqB, oaccB, lB, st, q0B, w, quad, lr);
  }

  // epilogue: reduce l, normalize, store both q-tiles
#pragma unroll
  for (int half = 0; half < 2; half++) {
    const int q0 = half ? q0B : q0A;
    f32x4(&oacc)[2][4] = half ? oaccB : oaccA;
    float* l_part = half ? lB : lA;
    float linv[2];
#pragma unroll
    for (int i = 0; i < 2; i++) {
      float l = l_part[i];
      l += __shfl_xor(l, 16, 64);
      l += __shfl_xor(l, 32, 64);
      linv[i] = 1.f / l;
    }
    uint16_t* ob =
        ctx + ((size_t)b * T_ + q0 + w * 32 + quad * 4) * D_ + h * 64 + lr;
#pragma unroll
    for (int i = 0; i < 2; i++)
#pragma unroll
      for (int r = 0; r < 4; r++) {
        const float inv = __shfl(linv[i], quad * 4 + r, 64);
#pragma unroll
        for (int j = 0; j < 4; j++)
          ob[(size_t)(i * 16 + r) * D_ + j * 16] = f2bf(oacc[i][j][r] * inv);
      }
  }
}

extern "C" void kernel_launch(void* const* d_in, const int* in_sizes, int n_in,
                              void* d_out, int out_size, void* d_ws, size_t ws_size,
                              hipStream_t stream) {
  const float* x = (const float*)d_in[0];
  const float* Wq = (const float*)d_in[1];
  const float* Wk = (const float*)d_in[2];
  const float* Wv = (const float*)d_in[3];
  const float* Wo = (const float*)d_in[4];
  const float* bo = (const float*)d_in[5];
  const float* W1 = (const float*)d_in[6];
  const float* b1 = (const float*)d_in[7];
  const float* W2 = (const float*)d_in[8];
  const float* b2 = (const float*)d_in[9];
  const float* g1 = (const float*)d_in[10];
  const float* be1 = (const float*)d_in[11];
  const float* g2 = (const float*)d_in[12];
  const float* be2 = (const float*)d_in[13];
  float* out = (float*)d_out;

  const size_t MB = 1024ull * 1024ull;
  if (ws_size < 200 * MB) return;
  char* ws = (char*)d_ws;
  uint16_t* hbuf = (uint16_t*)(ws + 0 * MB);    // 16 MB (LN out, reused)
  uint16_t* wqkvt = (uint16_t*)(ws + 16 * MB);  // 6 MB  [3072][1024]
  uint16_t* wot = (uint16_t*)(ws + 22 * MB);    // 2 MB  [1024][1024]
  uint16_t* w1t = (uint16_t*)(ws + 24 * MB);    // 8 MB  [4096][1024]
  uint16_t* w2t = (uint16_t*)(ws + 32 * MB);    // 8 MB  [1024][4096]
  float* x1 = (float*)(ws + 40 * MB);           // 32 MB
  uint16_t* qkvb = (uint16_t*)(ws + 72 * MB);   // 48 MB [8192][3072]
  uint16_t* ctxb = (uint16_t*)(ws + 120 * MB);  // 16 MB [8192][1024]
  uint16_t* vtb = (uint16_t*)(ws + 136 * MB);   // 16 MB (dead before ffb written)
  uint16_t* ffb = (uint16_t*)(ws + 136 * MB);   // 64 MB [8192][4096]

  prep_ln<<<20480, 256, 0, stream>>>(x, g1, be1, hbuf, Wq, Wk, Wv, Wo, W1, W2,
                                     wqkvt, wot, w1t, w2t);
  // QKV: M=8192, N=3072, K=1024 -> 32*12 = 384 blocks (8-phase 256^2)
  gemm_8ph<<<(M_ / 256) * (3 * D_ / 256), 512, 0, stream>>>(
      hbuf, wqkvt, qkvb, nullptr, nullptr, M_, 3 * D_, D_, D_, D_, 2);
  v_transpose<<<dim3(T_ / 64, B_ * H_), 256, 0, stream>>>(qkvb, vtb);
  attn_mfma<<<512, 256, 0, stream>>>(qkvb, vtb, ctxb);
  gemm_bf16<64><<<64 * 16, 256, 0, stream>>>(ctxb, wot, x1, bo, x, M_, D_, D_, D_,
                                             D_, 0);
  ln_bf16<<<M_, 256, 0, stream>>>(x1, g2, be2, hbuf);
  // FFN1: M=8192, N=4096, K=1024 -> 32*16 = 512 blocks (8-phase 256^2)
  gemm_8ph<<<(M_ / 256) * (DFF_ / 256), 512, 0, stream>>>(
      hbuf, w1t, ffb, b1, nullptr, M_, DFF_, D_, D_, D_, 1 | 2);
  gemm_bf16<64><<<64 * 16, 256, 0, stream>>>(ffb, w2t, out, b2, x1, M_, D_, DFF_,
                                             DFF_, DFF_, 0);
}

// Round 3
// 548.135 us; speedup vs baseline: 1.0214x; 1.0214x over previous
//
#include <hip/hip_runtime.h>
#include <stdint.h>

#define B_ 4
#define T_ 2048
#define D_ 1024
#define H_ 16
#define HD_ 64
#define DFF_ 4096
#define M_ (B_ * T_)  // 8192

typedef __bf16 bf16x8 __attribute__((ext_vector_type(8)));
typedef float f32x4 __attribute__((ext_vector_type(4)));

__device__ __forceinline__ uint16_t f2bf(float f) {
  union { float f; uint32_t u; } v;
  v.f = f;
  uint32_t r = v.u + 0x7FFF + ((v.u >> 16) & 1);  // RNE
  return (uint16_t)(r >> 16);
}

#define GLD_LDS(gp, lp)                                                        \
  __builtin_amdgcn_global_load_lds(                                            \
      (const __attribute__((address_space(1))) void*)(gp),                     \
      (__attribute__((address_space(3))) void*)(lp), 16, 0, 0)

// ---------------- LayerNorm fp32 -> bf16 (used for LN2) ----------------
__global__ __launch_bounds__(256) void ln_bf16(const float* __restrict__ x,
                                               const float* __restrict__ gamma,
                                               const float* __restrict__ beta,
                                               uint16_t* __restrict__ out) {
  __shared__ float red[4];
  const int tid = threadIdx.x;
  const size_t row = blockIdx.x;
  const float4 v = ((const float4*)(x + row * D_))[tid];
  float s = v.x + v.y + v.z + v.w;
#pragma unroll
  for (int off = 32; off >= 1; off >>= 1) s += __shfl_xor(s, off, 64);
  if ((tid & 63) == 0) red[tid >> 6] = s;
  __syncthreads();
  const float mean = (red[0] + red[1] + red[2] + red[3]) * (1.0f / D_);
  const float d0 = v.x - mean, d1 = v.y - mean, d2 = v.z - mean, d3 = v.w - mean;
  float ss = d0 * d0 + d1 * d1 + d2 * d2 + d3 * d3;
#pragma unroll
  for (int off = 32; off >= 1; off >>= 1) ss += __shfl_xor(ss, off, 64);
  __syncthreads();
  if ((tid & 63) == 0) red[tid >> 6] = ss;
  __syncthreads();
  const float var = (red[0] + red[1] + red[2] + red[3]) * (1.0f / D_);
  const float rstd = rsqrtf(var + 1e-5f);
  const float4 g = ((const float4*)gamma)[tid];
  const float4 b = ((const float4*)beta)[tid];
  ushort4 o;
  o.x = f2bf(d0 * rstd * g.x + b.x);
  o.y = f2bf(d1 * rstd * g.y + b.y);
  o.z = f2bf(d2 * rstd * g.z + b.z);
  o.w = f2bf(d3 * rstd * g.w + b.w);
  ((ushort4*)(out + row * D_))[tid] = o;
}

// ---- fused: LN1 (pid<8192) + weight prep (Wo/W1/W2 transposes + qkv rearrange) ----
__global__ __launch_bounds__(256) void prep_ln(
    const float* __restrict__ x, const float* __restrict__ g1,
    const float* __restrict__ be1, uint16_t* __restrict__ hbuf,
    const float* __restrict__ Wq, const float* __restrict__ Wk,
    const float* __restrict__ Wv, const float* __restrict__ Wo,
    const float* __restrict__ W1, const float* __restrict__ W2,
    uint16_t* __restrict__ wqkvt, uint16_t* __restrict__ wot,
    uint16_t* __restrict__ w1t, uint16_t* __restrict__ w2t) {
  const int pid = blockIdx.x;
  const int tid = threadIdx.x;

  if (pid < 8192) {  // LN1 row
    __shared__ float red[4];
    const size_t row = pid;
    const float4 v = ((const float4*)(x + row * D_))[tid];
    float s = v.x + v.y + v.z + v.w;
#pragma unroll
    for (int off = 32; off >= 1; off >>= 1) s += __shfl_xor(s, off, 64);
    if ((tid & 63) == 0) red[tid >> 6] = s;
    __syncthreads();
    const float mean = (red[0] + red[1] + red[2] + red[3]) * (1.0f / D_);
    const float d0 = v.x - mean, d1 = v.y - mean, d2 = v.z - mean, d3 = v.w - mean;
    float ss = d0 * d0 + d1 * d1 + d2 * d2 + d3 * d3;
#pragma unroll
    for (int off = 32; off >= 1; off >>= 1) ss += __shfl_xor(ss, off, 64);
    __syncthreads();
    if ((tid & 63) == 0) red[tid >> 6] = ss;
    __syncthreads();
    const float var = (red[0] + red[1] + red[2] + red[3]) * (1.0f / D_);
    const float rstd = rsqrtf(var + 1e-5f);
    const float4 g = ((const float4*)g1)[tid];
    const float4 b = ((const float4*)be1)[tid];
    ushort4 o;
    o.x = f2bf(d0 * rstd * g.x + b.x);
    o.y = f2bf(d1 * rstd * g.y + b.y);
    o.z = f2bf(d2 * rstd * g.z + b.z);
    o.w = f2bf(d3 * rstd * g.w + b.w);
    ((ushort4*)(hbuf + row * D_))[tid] = o;
    return;
  }

  __shared__ float tile[32][33];
  const int tx = tid & 31, ty = tid >> 5;
  const int q = pid - 8192;

  if (q >= 9216) {  // qkv rearrange [H][D][HD] -> [which*1024+h*64+e][D]
    const int p = q - 9216;
    const int bx = p & 1, by = (p >> 1) & 31, z = p >> 6;
    const int which = z >> 4, hh = z & 15;
    const float* W = (which == 0) ? Wq : ((which == 1) ? Wk : Wv);
    const float* in = W + (size_t)hh * D_ * HD_;
    const int e0 = bx * 32, d0 = by * 32;
#pragma unroll
    for (int i = 0; i < 32; i += 8)
      tile[ty + i][tx] = in[(size_t)(d0 + ty + i) * HD_ + e0 + tx];
    __syncthreads();
#pragma unroll
    for (int i = 0; i < 32; i += 8)
      wqkvt[((size_t)(which * 1024 + hh * 64) + e0 + ty + i) * D_ + d0 + tx] =
          f2bf(tile[tx][ty + i]);
    return;
  }

  const float* in;
  uint16_t* out;
  int R, C, bx, by;
  if (q < 1024) {
    in = Wo; out = wot; R = 1024; C = 1024; bx = q & 31; by = q >> 5;
  } else if (q < 5120) {
    const int p = q - 1024;
    in = W1; out = w1t; R = 1024; C = 4096; bx = p & 127; by = p >> 7;
  } else {
    const int p = q - 5120;
    in = W2; out = w2t; R = 4096; C = 1024; bx = p & 31; by = p >> 5;
  }
  const int c0 = bx * 32, r0 = by * 32;
#pragma unroll
  for (int i = 0; i < 32; i += 8)
    tile[ty + i][tx] = in[(size_t)(r0 + ty + i) * C + c0 + tx];
  __syncthreads();
#pragma unroll
  for (int i = 0; i < 32; i += 8)
    out[(size_t)(c0 + ty + i) * R + r0 + tx] = f2bf(tile[tx][ty + i]);
}

// ---------------- bf16 MFMA GEMM (2-phase 128-tile; kept for N=1024 shapes) ----
// flags: 1 = relu, 2 = bf16 output
template <int BN>
__global__ __launch_bounds__(256) void gemm_bf16(const uint16_t* __restrict__ A,
                                                 const uint16_t* __restrict__ Bt,
                                                 void* __restrict__ C,
                                                 const float* __restrict__ bias,
                                                 const float* __restrict__ resid,
                                                 int M, int N, int K, int lda,
                                                 int ldb, int flags) {
  constexpr int NJ = BN / 32;  // j-frags per wave
  __shared__ __align__(16) uint16_t As[128 * 64];
  __shared__ __align__(16) uint16_t Bs[BN * 64];
  const int tid = threadIdx.x;
  const int lane = tid & 63, w = tid >> 6;
  const int quad = lane >> 4, lr = lane & 15;
  const int wr = w >> 1, wc = w & 1;

  const int n_tiles = N / BN;
  const int pid = blockIdx.x;
  const int grp = 16 * n_tiles;
  const int gid = pid / grp;
  const int rem = pid - gid * grp;
  const int nt = rem / 16;
  const int mt = gid * 16 + (rem - nt * 16);
  const int bn0 = nt * BN, bm0 = mt * 128;

  f32x4 acc[4][NJ];
#pragma unroll
  for (int i = 0; i < 4; i++)
#pragma unroll
    for (int j = 0; j < NJ; j++) acc[i][j] = f32x4{0.f, 0.f, 0.f, 0.f};

  const int s_row = lane >> 3, s_slot = lane & 7;

  for (int k0 = 0; k0 < K; k0 += 64) {
#pragma unroll
    for (int u = 0; u < 4; u++) {
      const int r = w * 32 + u * 8 + s_row;
      const int cg = s_slot ^ (r & 7);
      GLD_LDS(A + (size_t)(bm0 + r) * lda + k0 + cg * 8, As + (w * 32 + u * 8) * 64);
    }
#pragma unroll
    for (int u = 0; u < NJ; u++) {
      const int r = w * (BN / 4) + u * 8 + s_row;
      const int cg = s_slot ^ (r & 7);
      GLD_LDS(Bt + (size_t)(bn0 + r) * ldb + k0 + cg * 8,
              Bs + (w * (BN / 4) + u * 8) * 64);
    }
    __syncthreads();

#pragma unroll
    for (int ks = 0; ks < 2; ks++) {
      bf16x8 af[4], bfr[NJ];
#pragma unroll
      for (int i = 0; i < 4; i++) {
        const int m = wr * 64 + i * 16 + lr;
        const int slot = (ks * 4 + quad) ^ (m & 7);
        af[i] = *(const bf16x8*)(As + m * 64 + slot * 8);
      }
#pragma unroll
      for (int j = 0; j < NJ; j++) {
        const int n = wc * (BN / 2) + j * 16 + lr;
        const int slot = (ks * 4 + quad) ^ (n & 7);
        bfr[j] = *(const bf16x8*)(Bs + n * 64 + slot * 8);
      }
#pragma unroll
      for (int i = 0; i < 4; i++)
#pragma unroll
        for (int j = 0; j < NJ; j++)
          acc[i][j] =
              __builtin_amdgcn_mfma_f32_16x16x32_bf16(af[i], bfr[j], acc[i][j], 0, 0, 0);
    }
    __syncthreads();
  }

  const int base_m = bm0 + wr * 64 + quad * 4;
  const int base_n = bn0 + wc * (BN / 2) + lr;
#pragma unroll
  for (int i = 0; i < 4; i++) {
#pragma unroll
    for (int j = 0; j < NJ; j++) {
      const int col = base_n + j * 16;
      const float bv = bias ? bias[col] : 0.f;
#pragma unroll
      for (int r = 0; r < 4; r++) {
        const size_t row = base_m + i * 16 + r;
        float v = acc[i][j][r] + bv;
        if (resid) v += resid[row * N + col];
        if (flags & 1) v = fmaxf(v, 0.f);
        if (flags & 2)
          ((uint16_t*)C)[row * N + col] = f2bf(v);
        else
          ((float*)C)[row * N + col] = v;
      }
    }
  }
}

// ---------------- 256x256 4-phase bf16 MFMA GEMM, counted vmcnt (T2+T3+T4+T5) ----
// 512 threads = 8 waves (2M x 4N). BK=64, double-buffered 128 KiB LDS.
// Staging issue order per tile (8 gld_lds/thread): B rows (4), A phase-1 rows (2),
// A phase-2 rows (2). Counted waits, never drain in steady state:
//   P1 end: vmcnt(8) -> retires ONLY prev tile's A-phase-2 pair (4-phase cover)
//   P4 end: vmcnt(2) -> retires next tile's B + A-phase-1 (3-phase cover),
//           leaving its A-phase-2 pair in flight across the tile boundary.
// Every wait sits before a shared s_barrier so cross-wave staged data is visible.
// Last tile peeled (vmcnt(0) there, else the counted wait is a no-op -> race).
// Requires M%256==0, N%256==0, K%64==0 and K>=128, grid%8==0.
#define STAGE8(buf, kt)                                                        \
  do {                                                                         \
    const int k0s = (kt) * 64;                                                 \
    _Pragma("unroll") for (int u = 0; u < 4; u++) {                            \
      const int r = w * 32 + u * 8 + s_row;                                    \
      const int cg = s_slot ^ (r & 7);                                         \
      GLD_LDS(Bt + (size_t)(bn0 + r) * ldb + k0s + cg * 8,                     \
              &Bs[buf][(w * 32 + u * 8) * 64]);                                \
    }                                                                          \
    const int rb = (w >> 2) * 128 + (w & 3) * 16;                              \
    _Pragma("unroll") for (int u = 0; u < 2; u++) {                            \
      const int r = rb + u * 8 + s_row;                                        \
      const int cg = s_slot ^ (r & 7);                                         \
      GLD_LDS(A + (size_t)(bm0 + r) * lda + k0s + cg * 8,                      \
              &As[buf][(rb + u * 8) * 64]);                                    \
    }                                                                          \
    _Pragma("unroll") for (int u = 0; u < 2; u++) {                            \
      const int r = rb + 64 + u * 8 + s_row;                                   \
      const int cg = s_slot ^ (r & 7);                                         \
      GLD_LDS(A + (size_t)(bm0 + r) * lda + k0s + cg * 8,                      \
              &As[buf][(rb + 64 + u * 8) * 64]);                               \
    }                                                                          \
  } while (0)

#define RD_A8(dst, ibase, ks)                                                  \
  _Pragma("unroll") for (int i = 0; i < 4; i++) {                              \
    const int m = wr * 128 + ((ibase) + i) * 16 + lr;                          \
    const int slot = ((ks) * 4 + quad) ^ (m & 7);                              \
    dst[i] = *(const bf16x8*)(&As[c][m * 64 + slot * 8]);                      \
  }

#define RD_B8(dst, ks)                                                         \
  _Pragma("unroll") for (int j = 0; j < 4; j++) {                              \
    const int n = wc * 64 + j * 16 + lr;                                       \
    const int slot = ((ks) * 4 + quad) ^ (n & 7);                              \
    dst[j] = *(const bf16x8*)(&Bs[c][n * 64 + slot * 8]);                      \
  }

#define MFMA16(ibase, aarr)                                                    \
  do {                                                                         \
    __builtin_amdgcn_s_setprio(1);                                             \
    _Pragma("unroll") for (int i = 0; i < 4; i++)                              \
        _Pragma("unroll") for (int j = 0; j < 4; j++) acc[(ibase) + i][j] =    \
        __builtin_amdgcn_mfma_f32_16x16x32_bf16(aarr[i], bb[j],                \
                                                acc[(ibase) + i][j], 0, 0, 0); \
    __builtin_amdgcn_s_setprio(0);                                             \
  } while (0)

#define VMW(n) asm volatile("s_waitcnt vmcnt(" #n ")" ::: "memory")

__global__ __launch_bounds__(512, 2) void gemm_8ph(
    const uint16_t* __restrict__ A, const uint16_t* __restrict__ Bt,
    void* __restrict__ C, const float* __restrict__ bias,
    const float* __restrict__ resid, int M, int N, int K, int lda, int ldb,
    int flags) {
  __shared__ __align__(16) uint16_t As[2][256 * 64];  // 64 KiB
  __shared__ __align__(16) uint16_t Bs[2][256 * 64];  // 64 KiB
  const int tid = threadIdx.x;
  const int lane = tid & 63, w = tid >> 6;
  const int quad = lane >> 4, lr = lane & 15;
  const int wr = w >> 2, wc = w & 3;  // 2 x 4 wave grid; per-wave out 128x64
  const int s_row = lane >> 3, s_slot = lane & 7;

  // bijective XCD swizzle (grid % 8 == 0), then n-fastest raster.
  const int nwg = gridDim.x;
  const int cpx = nwg >> 3;
  const int pid0 = blockIdx.x;
  const int pid = (pid0 & 7) * cpx + (pid0 >> 3);
  const int n_tiles = N >> 8;
  const int mt = pid / n_tiles;
  const int nt = pid - mt * n_tiles;
  const int bm0 = mt * 256, bn0 = nt * 256;

  f32x4 acc[8][4];
#pragma unroll
  for (int i = 0; i < 8; i++)
#pragma unroll
    for (int j = 0; j < 4; j++) acc[i][j] = f32x4{0.f, 0.f, 0.f, 0.f};

  STAGE8(0, 0);
  VMW(2);  // tile 0: B + A-phase-1 landed; A-phase-2 pair stays in flight
  __builtin_amdgcn_s_barrier();

  const int NT = K >> 6;
  for (int t = 0; t < NT - 1; ++t) {
    const int c = t & 1;
    bf16x8 a_lo[4], a_hi[4], bb[4];
    // ---- P1: stage ALL of tile t+1, read ks=0 lo ----
    STAGE8(c ^ 1, t + 1);
    RD_A8(a_lo, 0, 0);
    RD_B8(bb, 0);
    __builtin_amdgcn_s_barrier();
    MFMA16(0, a_lo);
    VMW(8);  // retire prev tile's A-phase-2 pair (needed by P2)
    __builtin_amdgcn_s_barrier();
    // ---- P2: ks=0 hi ----
    RD_A8(a_hi, 4, 0);
    __builtin_amdgcn_s_barrier();
    MFMA16(4, a_hi);
    __builtin_amdgcn_s_barrier();
    // ---- P3: ks=1 lo ----
    RD_A8(a_lo, 0, 1);
    RD_B8(bb, 1);
    __builtin_amdgcn_s_barrier();
    MFMA16(0, a_lo);
    __builtin_amdgcn_s_barrier();
    // ---- P4: ks=1 hi; counted boundary wait ----
    RD_A8(a_hi, 4, 1);
    __builtin_amdgcn_s_barrier();
    MFMA16(4, a_hi);
    VMW(2);  // retire next tile's B + A-phase-1; A-phase-2 stays in flight
    __builtin_amdgcn_s_barrier();
  }
  {  // ---- peeled last tile: no staging; drain the final A-phase-2 pair ----
    const int c = (NT - 1) & 1;
    bf16x8 a_lo[4], a_hi[4], bb[4];
    RD_A8(a_lo, 0, 0);
    RD_B8(bb, 0);
    __builtin_amdgcn_s_barrier();
    MFMA16(0, a_lo);
    VMW(0);
    __builtin_amdgcn_s_barrier();
    RD_A8(a_hi, 4, 0);
    MFMA16(4, a_hi);
    RD_A8(a_lo, 0, 1);
    RD_B8(bb, 1);
    MFMA16(0, a_lo);
    RD_A8(a_hi, 4, 1);
    MFMA16(4, a_hi);
  }

  const int base_m = bm0 + wr * 128 + quad * 4;
  const int base_n = bn0 + wc * 64 + lr;
#pragma unroll
  for (int i = 0; i < 8; i++) {
#pragma unroll
    for (int j = 0; j < 4; j++) {
      const int col = base_n + j * 16;
      const float bv = bias ? bias[col] : 0.f;
#pragma unroll
      for (int r = 0; r < 4; r++) {
        const size_t row = base_m + i * 16 + r;
        float v = acc[i][j][r] + bv;
        if (resid) v += resid[row * N + col];
        if (flags & 1) v = fmaxf(v, 0.f);
        if (flags & 2)
          ((uint16_t*)C)[row * N + col] = f2bf(v);
        else
          ((float*)C)[row * N + col] = v;
      }
    }
  }
}

// ---- V transpose: qkv V-region [B*T][3072] -> vtb [(b*H+h)*64+e][T] bf16 ----
__global__ __launch_bounds__(256) void v_transpose(const uint16_t* __restrict__ qkv,
                                                   uint16_t* __restrict__ vtb) {
  __shared__ __align__(16) uint16_t tile[64 * 72];  // [t-local][e]
  const int tid = threadIdx.x;
  const int t0 = blockIdx.x * 64;
  const int bh = blockIdx.y;
  const int b = bh >> 4, h = bh & 15;
  const uint16_t* src = qkv + (size_t)b * T_ * 3072 + 2048 + h * 64;
#pragma unroll
  for (int u = 0; u < 2; u++) {
    const int uu = tid + u * 256;
    const int r = uu >> 3, c = uu & 7;
    *(int4*)(tile + r * 72 + c * 8) =
        *(const int4*)(src + (size_t)(t0 + r) * 3072 + c * 8);
  }
  __syncthreads();
  uint16_t* dst = vtb + ((size_t)bh * 64) * T_ + t0;
#pragma unroll
  for (int u = 0; u < 2; u++) {
    const int uu = tid + u * 256;
    const int e = uu >> 3, c2 = uu & 7;
    union { uint16_t u16[8]; int4 v; } tmp;
#pragma unroll
    for (int jj = 0; jj < 8; jj++) tmp.u16[jj] = tile[(c2 * 8 + jj) * 72 + e];
    *(int4*)(dst + (size_t)e * T_ + c2 * 8) = tmp.v;
  }
}

// ---- per-stage compute for one q-tile (S^T MFMA + static-max softmax + PV) ----
__device__ __forceinline__ void attn_tile_compute(
    const uint16_t* __restrict__ Kb, const uint16_t* __restrict__ Vb,
    uint16_t* __restrict__ Ps, const bf16x8 (&aq)[2][2], f32x4 (&oacc)[2][4],
    float (&l_part)[2], int st, int q0, int w, int quad, int lr) {
  const int lr7 = lr & 7;
  const int row_min_w = q0 + w * 32;

  // S^T = K @ Q^T : frag rows = s (4 sf-frags), cols = m (2 i-frags)
  f32x4 sa[2][4];
#pragma unroll
  for (int i = 0; i < 2; i++)
#pragma unroll
    for (int sf = 0; sf < 4; sf++) sa[i][sf] = f32x4{0.f, 0.f, 0.f, 0.f};
#pragma unroll
  for (int ks = 0; ks < 2; ks++) {
    bf16x8 ak[4];
#pragma unroll
    for (int sf = 0; sf < 4; sf++) {
      const int slot = (ks * 4 + quad) ^ lr7;
      ak[sf] = *(const bf16x8*)(Kb + (sf * 16 + lr) * 64 + slot * 8);
    }
#pragma unroll
    for (int i = 0; i < 2; i++)
#pragma unroll
      for (int sf = 0; sf < 4; sf++)
        sa[i][sf] =
            __builtin_amdgcn_mfma_f32_16x16x32_bf16(ak[sf], aq[i][ks], sa[i][sf], 0, 0, 0);
  }

  // p = exp2(s*log2e/8 - 20*log2e); mask only on the diagonal stage
  const bool diag = (st * 64 + 63 > row_min_w);
  if (diag) {
#pragma unroll
    for (int i = 0; i < 2; i++) {
      const int mrow = q0 + w * 32 + i * 16 + lr;
#pragma unroll
      for (int sf = 0; sf < 4; sf++) {
        const int s0 = st * 64 + sf * 16 + quad * 4;
        float p[4];
#pragma unroll
        for (int r = 0; r < 4; r++) {
          float sv = sa[i][sf][r];
          if (s0 + r > mrow) sv = -1e30f;
          p[r] = exp2f(fmaf(sv, 0.18033688f, -28.8539008f));
          l_part[i] += p[r];
        }
        ushort4 pk;
        pk.x = f2bf(p[0]);
        pk.y = f2bf(p[1]);
        pk.z = f2bf(p[2]);
        pk.w = f2bf(p[3]);
        *(ushort4*)(Ps + (size_t)(w * 32 + i * 16 + lr) * 72 + sf * 16 + quad * 4) = pk;
      }
    }
  } else {
#pragma unroll
    for (int i = 0; i < 2; i++) {
#pragma unroll
      for (int sf = 0; sf < 4; sf++) {
        float p[4];
#pragma unroll
        for (int r = 0; r < 4; r++) {
          p[r] = exp2f(fmaf(sa[i][sf][r], 0.18033688f, -28.8539008f));
          l_part[i] += p[r];
        }
        ushort4 pk;
        pk.x = f2bf(p[0]);
        pk.y = f2bf(p[1]);
        pk.z = f2bf(p[2]);
        pk.w = f2bf(p[3]);
        *(ushort4*)(Ps + (size_t)(w * 32 + i * 16 + lr) * 72 + sf * 16 + quad * 4) = pk;
      }
    }
  }

  // O += P @ V (per-wave LDS region, same-wave write->read)
#pragma unroll
  for (int ks = 0; ks < 2; ks++) {
    bf16x8 ap[2], bv[4];
#pragma unroll
    for (int i = 0; i < 2; i++)
      ap[i] = *(const bf16x8*)(Ps + (size_t)(w * 32 + i * 16 + lr) * 72 + ks * 32 +
                               quad * 8);
#pragma unroll
    for (int j = 0; j < 4; j++) {
      const int slot = (ks * 4 + quad) ^ lr7;
      bv[j] = *(const bf16x8*)(Vb + (j * 16 + lr) * 64 + slot * 8);
    }
#pragma unroll
    for (int i = 0; i < 2; i++)
#pragma unroll
      for (int j = 0; j < 4; j++)
        oacc[i][j] =
            __builtin_amdgcn_mfma_f32_16x16x32_bf16(ap[i], bv[j], oacc[i][j], 0, 0, 0);
  }
}

// ---------------- MFMA flash attention: paired q-tiles + XCD-local K/V ----------
__global__ __launch_bounds__(256) void attn_mfma(const uint16_t* __restrict__ qkv,
                                                 const uint16_t* __restrict__ vtb,
                                                 uint16_t* __restrict__ ctx) {
  __shared__ __align__(16) uint16_t Ks[64 * 64];   // [s][d] swizzled chunks
  __shared__ __align__(16) uint16_t Vt[64 * 64];   // [d][s] swizzled chunks
  __shared__ __align__(16) uint16_t Ps[128 * 72];  // [m][s] plain, padded
  const int tid = threadIdx.x;
  const int lane = tid & 63, w = tid >> 6;
  const int quad = lane >> 4, lr = lane & 15;
  const int pid = blockIdx.x;
  const int bh = pid & 63;         // same XCD for all i of this (b,h)
  const int i_pair = pid >> 6;     // 0..7
  const int b = bh >> 4, h = bh & 15;
  const uint16_t* base = qkv + (size_t)b * T_ * 3072 + h * 64;
  const uint16_t* vbase = vtb + ((size_t)bh * 64) * T_;
  const int s_row = lane >> 3, s_slot = lane & 7;

  const int tqA = i_pair, tqB = 15 - i_pair;
  const int q0A = tqA * 128, q0B = tqB * 128;
  const int nstgA = 2 * tqA + 2, nstgB = 2 * tqB + 2;
  const int nstg = (nstgA > nstgB) ? nstgA : nstgB;

  bf16x8 aqA[2][2], aqB[2][2];
#pragma unroll
  for (int i = 0; i < 2; i++)
#pragma unroll
    for (int ks = 0; ks < 2; ks++) {
      aqA[i][ks] = *(const bf16x8*)(base + (size_t)(q0A + w * 32 + i * 16 + lr) * 3072 +
                                    ks * 32 + quad * 8);
      aqB[i][ks] = *(const bf16x8*)(base + (size_t)(q0B + w * 32 + i * 16 + lr) * 3072 +
                                    ks * 32 + quad * 8);
    }

  f32x4 oaccA[2][4], oaccB[2][4];
#pragma unroll
  for (int i = 0; i < 2; i++)
#pragma unroll
    for (int j = 0; j < 4; j++) {
      oaccA[i][j] = f32x4{0.f, 0.f, 0.f, 0.f};
      oaccB[i][j] = f32x4{0.f, 0.f, 0.f, 0.f};
    }
  float lA[2] = {0.f, 0.f}, lB[2] = {0.f, 0.f};

  const int row_maxA = q0A + w * 32 + 31;
  const int row_maxB = q0B + w * 32 + 31;

  for (int st = 0; st < nstg; st++) {
    __syncthreads();  // prior stage's LDS reads complete
#pragma unroll
    for (int u = 0; u < 2; u++) {
      const int r = w * 16 + u * 8 + s_row;
      const int cg = s_slot ^ (r & 7);
      GLD_LDS(base + 1024 + (size_t)(st * 64 + r) * 3072 + cg * 8,
              Ks + (w * 16 + u * 8) * 64);
      GLD_LDS(vbase + (size_t)r * T_ + st * 64 + cg * 8, Vt + (w * 16 + u * 8) * 64);
    }
    __syncthreads();

    if (st < nstgA && st * 64 <= row_maxA)
      attn_tile_compute(Ks, Vt, Ps, aqA, oaccA, lA, st, q0A, w, quad, lr);
    if (st < nstgB && st * 64 <= row_maxB)
      attn_tile_compute(Ks, Vt, Ps, aqB, oaccB, lB, st, q0B, w, quad, lr);
  }

  // epilogue: reduce l, normalize, store both q-tiles
#pragma unroll
  for (int half = 0; half < 2; half++) {
    const int q0 = half ? q0B : q0A;
    f32x4(&oacc)[2][4] = half ? oaccB : oaccA;
    float* l_part = half ? lB : lA;
    float linv[2];
#pragma unroll
    for (int i = 0; i < 2; i++) {
      float l = l_part[i];
      l += __shfl_xor(l, 16, 64);
      l += __shfl_xor(l, 32, 64);
      linv[i] = 1.f / l;
    }
    uint16_t* ob =
        ctx + ((size_t)b * T_ + q0 + w * 32 + quad * 4) * D_ + h * 64 + lr;
#pragma unroll
    for (int i = 0; i < 2; i++)
#pragma unroll
      for (int r = 0; r < 4; r++) {
        const float inv = __shfl(linv[i], quad * 4 + r, 64);
#pragma unroll
        for (int j = 0; j < 4; j++)
          ob[(size_t)(i * 16 + r) * D_ + j * 16] = f2bf(oacc[i][j][r] * inv);
      }
  }
}

extern "C" void kernel_launch(void* const* d_in, const int* in_sizes, int n_in,
                              void* d_out, int out_size, void* d_ws, size_t ws_size,
                              hipStream_t stream) {
  const float* x = (const float*)d_in[0];
  const float* Wq = (const float*)d_in[1];
  const float* Wk = (const float*)d_in[2];
  const float* Wv = (const float*)d_in[3];
  const float* Wo = (const float*)d_in[4];
  const float* bo = (const float*)d_in[5];
  const float* W1 = (const float*)d_in[6];
  const float* b1 = (const float*)d_in[7];
  const float* W2 = (const float*)d_in[8];
  const float* b2 = (const float*)d_in[9];
  const float* g1 = (const float*)d_in[10];
  const float* be1 = (const float*)d_in[11];
  const float* g2 = (const float*)d_in[12];
  const float* be2 = (const float*)d_in[13];
  float* out = (float*)d_out;

  const size_t MB = 1024ull * 1024ull;
  if (ws_size < 200 * MB) return;
  char* ws = (char*)d_ws;
  uint16_t* hbuf = (uint16_t*)(ws + 0 * MB);    // 16 MB (LN out, reused)
  uint16_t* wqkvt = (uint16_t*)(ws + 16 * MB);  // 6 MB  [3072][1024]
  uint16_t* wot = (uint16_t*)(ws + 22 * MB);    // 2 MB  [1024][1024]
  uint16_t* w1t = (uint16_t*)(ws + 24 * MB);    // 8 MB  [4096][1024]
  uint16_t* w2t = (uint16_t*)(ws + 32 * MB);    // 8 MB  [1024][4096]
  float* x1 = (float*)(ws + 40 * MB);           // 32 MB
  uint16_t* qkvb = (uint16_t*)(ws + 72 * MB);   // 48 MB [8192][3072]
  uint16_t* ctxb = (uint16_t*)(ws + 120 * MB);  // 16 MB [8192][1024]
  uint16_t* vtb = (uint16_t*)(ws + 136 * MB);   // 16 MB (dead before ffb written)
  uint16_t* ffb = (uint16_t*)(ws + 136 * MB);   // 64 MB [8192][4096]

  prep_ln<<<20480, 256, 0, stream>>>(x, g1, be1, hbuf, Wq, Wk, Wv, Wo, W1, W2,
                                     wqkvt, wot, w1t, w2t);
  // QKV: M=8192, N=3072, K=1024 -> 384 blocks (256^2, counted-vmcnt phases)
  gemm_8ph<<<(M_ / 256) * (3 * D_ / 256), 512, 0, stream>>>(
      hbuf, wqkvt, qkvb, nullptr, nullptr, M_, 3 * D_, D_, D_, D_, 2);
  v_transpose<<<dim3(T_ / 64, B_ * H_), 256, 0, stream>>>(qkvb, vtb);
  attn_mfma<<<512, 256, 0, stream>>>(qkvb, vtb, ctxb);
  gemm_bf16<64><<<64 * 16, 256, 0, stream>>>(ctxb, wot, x1, bo, x, M_, D_, D_, D_,
                                             D_, 0);
  ln_bf16<<<M_, 256, 0, stream>>>(x1, g2, be2, hbuf);
  // FFN1: M=8192, N=4096, K=1024 -> 512 blocks (256^2, counted-vmcnt phases)
  gemm_8ph<<<(M_ / 256) * (DFF_ / 256), 512, 0, stream>>>(
      hbuf, w1t, ffb, b1, nullptr, M_, DFF_, D_, D_, D_, 1 | 2);
  gemm_bf16<64><<<64 * 16, 256, 0, stream>>>(ffb, w2t, out, b2, x1, M_, D_, DFF_,
                                             DFF_, DFF_, 0);
}

// Round 4
// 541.001 us; speedup vs baseline: 1.0349x; 1.0132x over previous
//
#include <hip/hip_runtime.h>
#include <stdint.h>

#define B_ 4
#define T_ 2048
#define D_ 1024
#define H_ 16
#define HD_ 64
#define DFF_ 4096
#define M_ (B_ * T_)  // 8192

typedef __bf16 bf16x8 __attribute__((ext_vector_type(8)));
typedef float f32x4 __attribute__((ext_vector_type(4)));

__device__ __forceinline__ uint16_t f2bf(float f) {
  union { float f; uint32_t u; } v;
  v.f = f;
  uint32_t r = v.u + 0x7FFF + ((v.u >> 16) & 1);  // RNE
  return (uint16_t)(r >> 16);
}

#define GLD_LDS(gp, lp)                                                        \
  __builtin_amdgcn_global_load_lds(                                            \
      (const __attribute__((address_space(1))) void*)(gp),                     \
      (__attribute__((address_space(3))) void*)(lp), 16, 0, 0)

// ---------------- LayerNorm fp32 -> bf16 (used for LN2) ----------------
__global__ __launch_bounds__(256) void ln_bf16(const float* __restrict__ x,
                                               const float* __restrict__ gamma,
                                               const float* __restrict__ beta,
                                               uint16_t* __restrict__ out) {
  __shared__ float red[4];
  const int tid = threadIdx.x;
  const size_t row = blockIdx.x;
  const float4 v = ((const float4*)(x + row * D_))[tid];
  float s = v.x + v.y + v.z + v.w;
#pragma unroll
  for (int off = 32; off >= 1; off >>= 1) s += __shfl_xor(s, off, 64);
  if ((tid & 63) == 0) red[tid >> 6] = s;
  __syncthreads();
  const float mean = (red[0] + red[1] + red[2] + red[3]) * (1.0f / D_);
  const float d0 = v.x - mean, d1 = v.y - mean, d2 = v.z - mean, d3 = v.w - mean;
  float ss = d0 * d0 + d1 * d1 + d2 * d2 + d3 * d3;
#pragma unroll
  for (int off = 32; off >= 1; off >>= 1) ss += __shfl_xor(ss, off, 64);
  __syncthreads();
  if ((tid & 63) == 0) red[tid >> 6] = ss;
  __syncthreads();
  const float var = (red[0] + red[1] + red[2] + red[3]) * (1.0f / D_);
  const float rstd = rsqrtf(var + 1e-5f);
  const float4 g = ((const float4*)gamma)[tid];
  const float4 b = ((const float4*)beta)[tid];
  ushort4 o;
  o.x = f2bf(d0 * rstd * g.x + b.x);
  o.y = f2bf(d1 * rstd * g.y + b.y);
  o.z = f2bf(d2 * rstd * g.z + b.z);
  o.w = f2bf(d3 * rstd * g.w + b.w);
  ((ushort4*)(out + row * D_))[tid] = o;
}

// ---- fused: LN1 (pid<8192) + weight prep (Wo/W1/W2 transposes + qkv rearrange) ----
// pid: [0,8192) LN1 rows; [8192,9216) Wo^T; [9216,13312) W1^T; [13312,17408) W2^T;
//      [17408,20480) qkv rearrange.
__global__ __launch_bounds__(256) void prep_ln(
    const float* __restrict__ x, const float* __restrict__ g1,
    const float* __restrict__ be1, uint16_t* __restrict__ hbuf,
    const float* __restrict__ Wq, const float* __restrict__ Wk,
    const float* __restrict__ Wv, const float* __restrict__ Wo,
    const float* __restrict__ W1, const float* __restrict__ W2,
    uint16_t* __restrict__ wqkvt, uint16_t* __restrict__ wot,
    uint16_t* __restrict__ w1t, uint16_t* __restrict__ w2t) {
  const int pid = blockIdx.x;
  const int tid = threadIdx.x;

  if (pid < 8192) {  // LN1 row
    __shared__ float red[4];
    const size_t row = pid;
    const float4 v = ((const float4*)(x + row * D_))[tid];
    float s = v.x + v.y + v.z + v.w;
#pragma unroll
    for (int off = 32; off >= 1; off >>= 1) s += __shfl_xor(s, off, 64);
    if ((tid & 63) == 0) red[tid >> 6] = s;
    __syncthreads();
    const float mean = (red[0] + red[1] + red[2] + red[3]) * (1.0f / D_);
    const float d0 = v.x - mean, d1 = v.y - mean, d2 = v.z - mean, d3 = v.w - mean;
    float ss = d0 * d0 + d1 * d1 + d2 * d2 + d3 * d3;
#pragma unroll
    for (int off = 32; off >= 1; off >>= 1) ss += __shfl_xor(ss, off, 64);
    __syncthreads();
    if ((tid & 63) == 0) red[tid >> 6] = ss;
    __syncthreads();
    const float var = (red[0] + red[1] + red[2] + red[3]) * (1.0f / D_);
    const float rstd = rsqrtf(var + 1e-5f);
    const float4 g = ((const float4*)g1)[tid];
    const float4 b = ((const float4*)be1)[tid];
    ushort4 o;
    o.x = f2bf(d0 * rstd * g.x + b.x);
    o.y = f2bf(d1 * rstd * g.y + b.y);
    o.z = f2bf(d2 * rstd * g.z + b.z);
    o.w = f2bf(d3 * rstd * g.w + b.w);
    ((ushort4*)(hbuf + row * D_))[tid] = o;
    return;
  }

  __shared__ float tile[32][33];
  const int tx = tid & 31, ty = tid >> 5;
  const int q = pid - 8192;

  if (q >= 9216) {  // qkv rearrange [H][D][HD] -> [which*1024+h*64+e][D]
    const int p = q - 9216;
    const int bx = p & 1, by = (p >> 1) & 31, z = p >> 6;
    const int which = z >> 4, hh = z & 15;
    const float* W = (which == 0) ? Wq : ((which == 1) ? Wk : Wv);
    const float* in = W + (size_t)hh * D_ * HD_;
    const int e0 = bx * 32, d0 = by * 32;
#pragma unroll
    for (int i = 0; i < 32; i += 8)
      tile[ty + i][tx] = in[(size_t)(d0 + ty + i) * HD_ + e0 + tx];
    __syncthreads();
#pragma unroll
    for (int i = 0; i < 32; i += 8)
      wqkvt[((size_t)(which * 1024 + hh * 64) + e0 + ty + i) * D_ + d0 + tx] =
          f2bf(tile[tx][ty + i]);
    return;
  }

  const float* in;
  uint16_t* out;
  int R, C, bx, by;
  if (q < 1024) {
    in = Wo; out = wot; R = 1024; C = 1024; bx = q & 31; by = q >> 5;
  } else if (q < 5120) {
    const int p = q - 1024;
    in = W1; out = w1t; R = 1024; C = 4096; bx = p & 127; by = p >> 7;
  } else {
    const int p = q - 5120;
    in = W2; out = w2t; R = 4096; C = 1024; bx = p & 31; by = p >> 5;
  }
  const int c0 = bx * 32, r0 = by * 32;
#pragma unroll
  for (int i = 0; i < 32; i += 8)
    tile[ty + i][tx] = in[(size_t)(r0 + ty + i) * C + c0 + tx];
  __syncthreads();
#pragma unroll
  for (int i = 0; i < 32; i += 8)
    out[(size_t)(c0 + ty + i) * R + r0 + tx] = f2bf(tile[tx][ty + i]);
}

// ---------------- bf16 MFMA GEMM: C[M,N] = A[M,K] @ Bt[N,K]^T ----------------
// BM=128, BN template (128 for all shapes now), BK=64, 4 waves (2x2).
// GROUP_M=16 grouped raster. XOR chunk swizzle: 2-way LDS aliasing (free).
// flags: 1 = relu, 2 = bf16 output
template <int BN>
__global__ __launch_bounds__(256) void gemm_bf16(const uint16_t* __restrict__ A,
                                                 const uint16_t* __restrict__ Bt,
                                                 void* __restrict__ C,
                                                 const float* __restrict__ bias,
                                                 const float* __restrict__ resid,
                                                 int M, int N, int K, int lda,
                                                 int ldb, int flags) {
  constexpr int NJ = BN / 32;  // j-frags per wave
  __shared__ __align__(16) uint16_t As[128 * 64];
  __shared__ __align__(16) uint16_t Bs[BN * 64];
  const int tid = threadIdx.x;
  const int lane = tid & 63, w = tid >> 6;
  const int quad = lane >> 4, lr = lane & 15;
  const int wr = w >> 1, wc = w & 1;

  const int n_tiles = N / BN;
  const int pid = blockIdx.x;
  const int grp = 16 * n_tiles;
  const int gid = pid / grp;
  const int rem = pid - gid * grp;
  const int nt = rem / 16;
  const int mt = gid * 16 + (rem - nt * 16);
  const int bn0 = nt * BN, bm0 = mt * 128;

  f32x4 acc[4][NJ];
#pragma unroll
  for (int i = 0; i < 4; i++)
#pragma unroll
    for (int j = 0; j < NJ; j++) acc[i][j] = f32x4{0.f, 0.f, 0.f, 0.f};

  const int s_row = lane >> 3, s_slot = lane & 7;

  for (int k0 = 0; k0 < K; k0 += 64) {
#pragma unroll
    for (int u = 0; u < 4; u++) {
      const int r = w * 32 + u * 8 + s_row;
      const int cg = s_slot ^ (r & 7);
      GLD_LDS(A + (size_t)(bm0 + r) * lda + k0 + cg * 8, As + (w * 32 + u * 8) * 64);
    }
#pragma unroll
    for (int u = 0; u < NJ; u++) {
      const int r = w * (BN / 4) + u * 8 + s_row;
      const int cg = s_slot ^ (r & 7);
      GLD_LDS(Bt + (size_t)(bn0 + r) * ldb + k0 + cg * 8,
              Bs + (w * (BN / 4) + u * 8) * 64);
    }
    __syncthreads();

#pragma unroll
    for (int ks = 0; ks < 2; ks++) {
      bf16x8 af[4], bfr[NJ];
#pragma unroll
      for (int i = 0; i < 4; i++) {
        const int m = wr * 64 + i * 16 + lr;
        const int slot = (ks * 4 + quad) ^ (m & 7);
        af[i] = *(const bf16x8*)(As + m * 64 + slot * 8);
      }
#pragma unroll
      for (int j = 0; j < NJ; j++) {
        const int n = wc * (BN / 2) + j * 16 + lr;
        const int slot = (ks * 4 + quad) ^ (n & 7);
        bfr[j] = *(const bf16x8*)(Bs + n * 64 + slot * 8);
      }
#pragma unroll
      for (int i = 0; i < 4; i++)
#pragma unroll
        for (int j = 0; j < NJ; j++)
          acc[i][j] =
              __builtin_amdgcn_mfma_f32_16x16x32_bf16(af[i], bfr[j], acc[i][j], 0, 0, 0);
    }
    __syncthreads();
  }

  const int base_m = bm0 + wr * 64 + quad * 4;
  const int base_n = bn0 + wc * (BN / 2) + lr;
#pragma unroll
  for (int i = 0; i < 4; i++) {
#pragma unroll
    for (int j = 0; j < NJ; j++) {
      const int col = base_n + j * 16;
      const float bv = bias ? bias[col] : 0.f;
#pragma unroll
      for (int r = 0; r < 4; r++) {
        const size_t row = base_m + i * 16 + r;
        float v = acc[i][j][r] + bv;
        if (resid) v += resid[row * N + col];
        if (flags & 1) v = fmaxf(v, 0.f);
        if (flags & 2)
          ((uint16_t*)C)[row * N + col] = f2bf(v);
        else
          ((float*)C)[row * N + col] = v;
      }
    }
  }
}

// ---- V transpose: qkv V-region [B*T][3072] -> vtb [(b*H+h)*64+e][T] bf16 ----
__global__ __launch_bounds__(256) void v_transpose(const uint16_t* __restrict__ qkv,
                                                   uint16_t* __restrict__ vtb) {
  __shared__ __align__(16) uint16_t tile[64 * 72];  // [t-local][e]
  const int tid = threadIdx.x;
  const int t0 = blockIdx.x * 64;
  const int bh = blockIdx.y;
  const int b = bh >> 4, h = bh & 15;
  const uint16_t* src = qkv + (size_t)b * T_ * 3072 + 2048 + h * 64;
#pragma unroll
  for (int u = 0; u < 2; u++) {
    const int uu = tid + u * 256;
    const int r = uu >> 3, c = uu & 7;
    *(int4*)(tile + r * 72 + c * 8) =
        *(const int4*)(src + (size_t)(t0 + r) * 3072 + c * 8);
  }
  __syncthreads();
  uint16_t* dst = vtb + ((size_t)bh * 64) * T_ + t0;
#pragma unroll
  for (int u = 0; u < 2; u++) {
    const int uu = tid + u * 256;
    const int e = uu >> 3, c2 = uu & 7;
    union { uint16_t u16[8]; int4 v; } tmp;
#pragma unroll
    for (int jj = 0; jj < 8; jj++) tmp.u16[jj] = tile[(c2 * 8 + jj) * 72 + e];
    *(int4*)(dst + (size_t)e * T_ + c2 * 8) = tmp.v;
  }
}

// ---- per-stage compute for one q-tile (S^T MFMA + static-max softmax + PV) ----
__device__ __forceinline__ void attn_tile_compute(
    const uint16_t* __restrict__ Kb, const uint16_t* __restrict__ Vb,
    uint16_t* __restrict__ Ps, const bf16x8 (&aq)[2][2], f32x4 (&oacc)[2][4],
    float (&l_part)[2], int st, int q0, int w, int quad, int lr) {
  const int lr7 = lr & 7;
  const int row_min_w = q0 + w * 32;

  // S^T = K @ Q^T : frag rows = s (4 sf-frags), cols = m (2 i-frags)
  f32x4 sa[2][4];
#pragma unroll
  for (int i = 0; i < 2; i++)
#pragma unroll
    for (int sf = 0; sf < 4; sf++) sa[i][sf] = f32x4{0.f, 0.f, 0.f, 0.f};
#pragma unroll
  for (int ks = 0; ks < 2; ks++) {
    bf16x8 ak[4];
#pragma unroll
    for (int sf = 0; sf < 4; sf++) {
      const int slot = (ks * 4 + quad) ^ lr7;
      ak[sf] = *(const bf16x8*)(Kb + (sf * 16 + lr) * 64 + slot * 8);
    }
#pragma unroll
    for (int i = 0; i < 2; i++)
#pragma unroll
      for (int sf = 0; sf < 4; sf++)
        sa[i][sf] =
            __builtin_amdgcn_mfma_f32_16x16x32_bf16(ak[sf], aq[i][ks], sa[i][sf], 0, 0, 0);
  }

  // p = exp2(s*log2e/8 - 20*log2e); mask only on the diagonal stage
  const bool diag = (st * 64 + 63 > row_min_w);
  if (diag) {
#pragma unroll
    for (int i = 0; i < 2; i++) {
      const int mrow = q0 + w * 32 + i * 16 + lr;
#pragma unroll
      for (int sf = 0; sf < 4; sf++) {
        const int s0 = st * 64 + sf * 16 + quad * 4;
        float p[4];
#pragma unroll
        for (int r = 0; r < 4; r++) {
          float sv = sa[i][sf][r];
          if (s0 + r > mrow) sv = -1e30f;
          p[r] = exp2f(fmaf(sv, 0.18033688f, -28.8539008f));
          l_part[i] += p[r];
        }
        ushort4 pk;
        pk.x = f2bf(p[0]);
        pk.y = f2bf(p[1]);
        pk.z = f2bf(p[2]);
        pk.w = f2bf(p[3]);
        *(ushort4*)(Ps + (size_t)(w * 32 + i * 16 + lr) * 72 + sf * 16 + quad * 4) = pk;
      }
    }
  } else {
#pragma unroll
    for (int i = 0; i < 2; i++) {
#pragma unroll
      for (int sf = 0; sf < 4; sf++) {
        float p[4];
#pragma unroll
        for (int r = 0; r < 4; r++) {
          p[r] = exp2f(fmaf(sa[i][sf][r], 0.18033688f, -28.8539008f));
          l_part[i] += p[r];
        }
        ushort4 pk;
        pk.x = f2bf(p[0]);
        pk.y = f2bf(p[1]);
        pk.z = f2bf(p[2]);
        pk.w = f2bf(p[3]);
        *(ushort4*)(Ps + (size_t)(w * 32 + i * 16 + lr) * 72 + sf * 16 + quad * 4) = pk;
      }
    }
  }

  // O += P @ V (per-wave LDS region, same-wave write->read)
#pragma unroll
  for (int ks = 0; ks < 2; ks++) {
    bf16x8 ap[2], bv[4];
#pragma unroll
    for (int i = 0; i < 2; i++)
      ap[i] = *(const bf16x8*)(Ps + (size_t)(w * 32 + i * 16 + lr) * 72 + ks * 32 +
                               quad * 8);
#pragma unroll
    for (int j = 0; j < 4; j++) {
      const int slot = (ks * 4 + quad) ^ lr7;
      bv[j] = *(const bf16x8*)(Vb + (j * 16 + lr) * 64 + slot * 8);
    }
#pragma unroll
    for (int i = 0; i < 2; i++)
#pragma unroll
      for (int j = 0; j < 4; j++)
        oacc[i][j] =
            __builtin_amdgcn_mfma_f32_16x16x32_bf16(ap[i], bv[j], oacc[i][j], 0, 0, 0);
  }
}

// ---------------- MFMA flash attention: paired q-tiles + XCD-local K/V ----------
// 1-D grid, pid = i*64 + (b*16+h): all 8 tq-pair blocks of one (b,h) share
// pid%8 -> same XCD -> K/V (512KB/head) served from that XCD's L2 after first
// touch (8 heads x 512KB = 4MB = one L2). Paired q-tiles (i, 15-i) share each
// staged s-tile (nested causal ranges).
__global__ __launch_bounds__(256) void attn_mfma(const uint16_t* __restrict__ qkv,
                                                 const uint16_t* __restrict__ vtb,
                                                 uint16_t* __restrict__ ctx) {
  __shared__ __align__(16) uint16_t Ks[64 * 64];   // [s][d] swizzled chunks
  __shared__ __align__(16) uint16_t Vt[64 * 64];   // [d][s] swizzled chunks
  __shared__ __align__(16) uint16_t Ps[128 * 72];  // [m][s] plain, padded
  const int tid = threadIdx.x;
  const int lane = tid & 63, w = tid >> 6;
  const int quad = lane >> 4, lr = lane & 15;
  const int pid = blockIdx.x;
  const int bh = pid & 63;         // same XCD for all i of this (b,h)
  const int i_pair = pid >> 6;     // 0..7
  const int b = bh >> 4, h = bh & 15;
  const uint16_t* base = qkv + (size_t)b * T_ * 3072 + h * 64;
  const uint16_t* vbase = vtb + ((size_t)bh * 64) * T_;
  const int s_row = lane >> 3, s_slot = lane & 7;

  const int tqA = i_pair, tqB = 15 - i_pair;
  const int q0A = tqA * 128, q0B = tqB * 128;
  const int nstgA = 2 * tqA + 2, nstgB = 2 * tqB + 2;
  const int nstg = (nstgA > nstgB) ? nstgA : nstgB;

  bf16x8 aqA[2][2], aqB[2][2];
#pragma unroll
  for (int i = 0; i < 2; i++)
#pragma unroll
    for (int ks = 0; ks < 2; ks++) {
      aqA[i][ks] = *(const bf16x8*)(base + (size_t)(q0A + w * 32 + i * 16 + lr) * 3072 +
                                    ks * 32 + quad * 8);
      aqB[i][ks] = *(const bf16x8*)(base + (size_t)(q0B + w * 32 + i * 16 + lr) * 3072 +
                                    ks * 32 + quad * 8);
    }

  f32x4 oaccA[2][4], oaccB[2][4];
#pragma unroll
  for (int i = 0; i < 2; i++)
#pragma unroll
    for (int j = 0; j < 4; j++) {
      oaccA[i][j] = f32x4{0.f, 0.f, 0.f, 0.f};
      oaccB[i][j] = f32x4{0.f, 0.f, 0.f, 0.f};
    }
  float lA[2] = {0.f, 0.f}, lB[2] = {0.f, 0.f};

  const int row_maxA = q0A + w * 32 + 31;
  const int row_maxB = q0B + w * 32 + 31;

  for (int st = 0; st < nstg; st++) {
    __syncthreads();  // prior stage's LDS reads complete
#pragma unroll
    for (int u = 0; u < 2; u++) {
      const int r = w * 16 + u * 8 + s_row;
      const int cg = s_slot ^ (r & 7);
      GLD_LDS(base + 1024 + (size_t)(st * 64 + r) * 3072 + cg * 8,
              Ks + (w * 16 + u * 8) * 64);
      GLD_LDS(vbase + (size_t)r * T_ + st * 64 + cg * 8, Vt + (w * 16 + u * 8) * 64);
    }
    __syncthreads();

    if (st < nstgA && st * 64 <= row_maxA)
      attn_tile_compute(Ks, Vt, Ps, aqA, oaccA, lA, st, q0A, w, quad, lr);
    if (st < nstgB && st * 64 <= row_maxB)
      attn_tile_compute(Ks, Vt, Ps, aqB, oaccB, lB, st, q0B, w, quad, lr);
  }

  // epilogue: reduce l, normalize, store both q-tiles
#pragma unroll
  for (int half = 0; half < 2; half++) {
    const int q0 = half ? q0B : q0A;
    f32x4(&oacc)[2][4] = half ? oaccB : oaccA;
    float* l_part = half ? lB : lA;
    float linv[2];
#pragma unroll
    for (int i = 0; i < 2; i++) {
      float l = l_part[i];
      l += __shfl_xor(l, 16, 64);
      l += __shfl_xor(l, 32, 64);
      linv[i] = 1.f / l;
    }
    uint16_t* ob =
        ctx + ((size_t)b * T_ + q0 + w * 32 + quad * 4) * D_ + h * 64 + lr;
#pragma unroll
    for (int i = 0; i < 2; i++)
#pragma unroll
      for (int r = 0; r < 4; r++) {
        const float inv = __shfl(linv[i], quad * 4 + r, 64);
#pragma unroll
        for (int j = 0; j < 4; j++)
          ob[(size_t)(i * 16 + r) * D_ + j * 16] = f2bf(oacc[i][j][r] * inv);
      }
  }
}

extern "C" void kernel_launch(void* const* d_in, const int* in_sizes, int n_in,
                              void* d_out, int out_size, void* d_ws, size_t ws_size,
                              hipStream_t stream) {
  const float* x = (const float*)d_in[0];
  const float* Wq = (const float*)d_in[1];
  const float* Wk = (const float*)d_in[2];
  const float* Wv = (const float*)d_in[3];
  const float* Wo = (const float*)d_in[4];
  const float* bo = (const float*)d_in[5];
  const float* W1 = (const float*)d_in[6];
  const float* b1 = (const float*)d_in[7];
  const float* W2 = (const float*)d_in[8];
  const float* b2 = (const float*)d_in[9];
  const float* g1 = (const float*)d_in[10];
  const float* be1 = (const float*)d_in[11];
  const float* g2 = (const float*)d_in[12];
  const float* be2 = (const float*)d_in[13];
  float* out = (float*)d_out;

  const size_t MB = 1024ull * 1024ull;
  if (ws_size < 200 * MB) return;
  char* ws = (char*)d_ws;
  uint16_t* hbuf = (uint16_t*)(ws + 0 * MB);    // 16 MB (LN out, reused)
  uint16_t* wqkvt = (uint16_t*)(ws + 16 * MB);  // 6 MB  [3072][1024]
  uint16_t* wot = (uint16_t*)(ws + 22 * MB);    // 2 MB  [1024][1024]
  uint16_t* w1t = (uint16_t*)(ws + 24 * MB);    // 8 MB  [4096][1024]
  uint16_t* w2t = (uint16_t*)(ws + 32 * MB);    // 8 MB  [1024][4096]
  float* x1 = (float*)(ws + 40 * MB);           // 32 MB
  uint16_t* qkvb = (uint16_t*)(ws + 72 * MB);   // 48 MB [8192][3072]
  uint16_t* ctxb = (uint16_t*)(ws + 120 * MB);  // 16 MB [8192][1024]
  uint16_t* vtb = (uint16_t*)(ws + 136 * MB);   // 16 MB (dead before ffb written)
  uint16_t* ffb = (uint16_t*)(ws + 136 * MB);   // 64 MB [8192][4096]

  prep_ln<<<20480, 256, 0, stream>>>(x, g1, be1, hbuf, Wq, Wk, Wv, Wo, W1, W2,
                                     wqkvt, wot, w1t, w2t);
  // QKV: M=8192, N=3072, K=1024 -> 2-phase 128^2 (proven best at K=1024)
  gemm_bf16<128><<<64 * 24, 256, 0, stream>>>(hbuf, wqkvt, qkvb, nullptr, nullptr,
                                              M_, 3 * D_, D_, D_, D_, 2);
  v_transpose<<<dim3(T_ / 64, B_ * H_), 256, 0, stream>>>(qkvb, vtb);
  attn_mfma<<<512, 256, 0, stream>>>(qkvb, vtb, ctxb);
  // Wo: M=8192, N=1024, K=1024 -> BN=128 (512 blocks)
  gemm_bf16<128><<<64 * 8, 256, 0, stream>>>(ctxb, wot, x1, bo, x, M_, D_, D_, D_,
                                             D_, 0);
  ln_bf16<<<M_, 256, 0, stream>>>(x1, g2, be2, hbuf);
  // FFN1: M=8192, N=4096, K=1024 -> 2-phase 128^2
  gemm_bf16<128><<<64 * 32, 256, 0, stream>>>(hbuf, w1t, ffb, b1, nullptr, M_, DFF_,
                                              D_, D_, D_, 1 | 2);
  // FFN2: M=8192, N=1024, K=4096 -> BN=128 (512 blocks; deep K amortizes staging,
  // doubled B-frag reuse vs BN=64)
  gemm_bf16<128><<<64 * 8, 256, 0, stream>>>(ffb, w2t, out, b2, x1, M_, D_, DFF_,
                                             DFF_, DFF_, 0);
}

// Round 5
// 521.950 us; speedup vs baseline: 1.0726x; 1.0365x over previous
//
#include <hip/hip_runtime.h>
#include <stdint.h>

#define B_ 4
#define T_ 2048
#define D_ 1024
#define H_ 16
#define HD_ 64
#define DFF_ 4096
#define M_ (B_ * T_)  // 8192

typedef __bf16 bf16x8 __attribute__((ext_vector_type(8)));
typedef float f32x4 __attribute__((ext_vector_type(4)));

__device__ __forceinline__ uint16_t f2bf(float f) {
  union { float f; uint32_t u; } v;
  v.f = f;
  uint32_t r = v.u + 0x7FFF + ((v.u >> 16) & 1);  // RNE
  return (uint16_t)(r >> 16);
}

#define GLD_LDS(gp, lp)                                                        \
  __builtin_amdgcn_global_load_lds(                                            \
      (const __attribute__((address_space(1))) void*)(gp),                     \
      (__attribute__((address_space(3))) void*)(lp), 16, 0, 0)

// ---------------- LayerNorm fp32 -> bf16 (used for LN2) ----------------
__global__ __launch_bounds__(256) void ln_bf16(const float* __restrict__ x,
                                               const float* __restrict__ gamma,
                                               const float* __restrict__ beta,
                                               uint16_t* __restrict__ out) {
  __shared__ float red[4];
  const int tid = threadIdx.x;
  const size_t row = blockIdx.x;
  const float4 v = ((const float4*)(x + row * D_))[tid];
  float s = v.x + v.y + v.z + v.w;
#pragma unroll
  for (int off = 32; off >= 1; off >>= 1) s += __shfl_xor(s, off, 64);
  if ((tid & 63) == 0) red[tid >> 6] = s;
  __syncthreads();
  const float mean = (red[0] + red[1] + red[2] + red[3]) * (1.0f / D_);
  const float d0 = v.x - mean, d1 = v.y - mean, d2 = v.z - mean, d3 = v.w - mean;
  float ss = d0 * d0 + d1 * d1 + d2 * d2 + d3 * d3;
#pragma unroll
  for (int off = 32; off >= 1; off >>= 1) ss += __shfl_xor(ss, off, 64);
  __syncthreads();
  if ((tid & 63) == 0) red[tid >> 6] = ss;
  __syncthreads();
  const float var = (red[0] + red[1] + red[2] + red[3]) * (1.0f / D_);
  const float rstd = rsqrtf(var + 1e-5f);
  const float4 g = ((const float4*)gamma)[tid];
  const float4 b = ((const float4*)beta)[tid];
  ushort4 o;
  o.x = f2bf(d0 * rstd * g.x + b.x);
  o.y = f2bf(d1 * rstd * g.y + b.y);
  o.z = f2bf(d2 * rstd * g.z + b.z);
  o.w = f2bf(d3 * rstd * g.w + b.w);
  ((ushort4*)(out + row * D_))[tid] = o;
}

// ---- fused: LN1 (pid<8192) + weight prep (Wo/W1/W2 transposes + qkv rearrange) ----
__global__ __launch_bounds__(256) void prep_ln(
    const float* __restrict__ x, const float* __restrict__ g1,
    const float* __restrict__ be1, uint16_t* __restrict__ hbuf,
    const float* __restrict__ Wq, const float* __restrict__ Wk,
    const float* __restrict__ Wv, const float* __restrict__ Wo,
    const float* __restrict__ W1, const float* __restrict__ W2,
    uint16_t* __restrict__ wqkvt, uint16_t* __restrict__ wot,
    uint16_t* __restrict__ w1t, uint16_t* __restrict__ w2t) {
  const int pid = blockIdx.x;
  const int tid = threadIdx.x;

  if (pid < 8192) {  // LN1 row
    __shared__ float red[4];
    const size_t row = pid;
    const float4 v = ((const float4*)(x + row * D_))[tid];
    float s = v.x + v.y + v.z + v.w;
#pragma unroll
    for (int off = 32; off >= 1; off >>= 1) s += __shfl_xor(s, off, 64);
    if ((tid & 63) == 0) red[tid >> 6] = s;
    __syncthreads();
    const float mean = (red[0] + red[1] + red[2] + red[3]) * (1.0f / D_);
    const float d0 = v.x - mean, d1 = v.y - mean, d2 = v.z - mean, d3 = v.w - mean;
    float ss = d0 * d0 + d1 * d1 + d2 * d2 + d3 * d3;
#pragma unroll
    for (int off = 32; off >= 1; off >>= 1) ss += __shfl_xor(ss, off, 64);
    __syncthreads();
    if ((tid & 63) == 0) red[tid >> 6] = ss;
    __syncthreads();
    const float var = (red[0] + red[1] + red[2] + red[3]) * (1.0f / D_);
    const float rstd = rsqrtf(var + 1e-5f);
    const float4 g = ((const float4*)g1)[tid];
    const float4 b = ((const float4*)be1)[tid];
    ushort4 o;
    o.x = f2bf(d0 * rstd * g.x + b.x);
    o.y = f2bf(d1 * rstd * g.y + b.y);
    o.z = f2bf(d2 * rstd * g.z + b.z);
    o.w = f2bf(d3 * rstd * g.w + b.w);
    ((ushort4*)(hbuf + row * D_))[tid] = o;
    return;
  }

  __shared__ float tile[32][33];
  const int tx = tid & 31, ty = tid >> 5;
  const int q = pid - 8192;

  if (q >= 9216) {  // qkv rearrange [H][D][HD] -> [which*1024+h*64+e][D]
    const int p = q - 9216;
    const int bx = p & 1, by = (p >> 1) & 31, z = p >> 6;
    const int which = z >> 4, hh = z & 15;
    const float* W = (which == 0) ? Wq : ((which == 1) ? Wk : Wv);
    const float* in = W + (size_t)hh * D_ * HD_;
    const int e0 = bx * 32, d0 = by * 32;
#pragma unroll
    for (int i = 0; i < 32; i += 8)
      tile[ty + i][tx] = in[(size_t)(d0 + ty + i) * HD_ + e0 + tx];
    __syncthreads();
#pragma unroll
    for (int i = 0; i < 32; i += 8)
      wqkvt[((size_t)(which * 1024 + hh * 64) + e0 + ty + i) * D_ + d0 + tx] =
          f2bf(tile[tx][ty + i]);
    return;
  }

  const float* in;
  uint16_t* out;
  int R, C, bx, by;
  if (q < 1024) {
    in = Wo; out = wot; R = 1024; C = 1024; bx = q & 31; by = q >> 5;
  } else if (q < 5120) {
    const int p = q - 1024;
    in = W1; out = w1t; R = 1024; C = 4096; bx = p & 127; by = p >> 7;
  } else {
    const int p = q - 5120;
    in = W2; out = w2t; R = 4096; C = 1024; bx = p & 31; by = p >> 5;
  }
  const int c0 = bx * 32, r0 = by * 32;
#pragma unroll
  for (int i = 0; i < 32; i += 8)
    tile[ty + i][tx] = in[(size_t)(r0 + ty + i) * C + c0 + tx];
  __syncthreads();
#pragma unroll
  for (int i = 0; i < 32; i += 8)
    out[(size_t)(c0 + ty + i) * R + r0 + tx] = f2bf(tile[tx][ty + i]);
}

// ---------------- bf16 MFMA GEMM (2-phase 128-tile) ----------------
// flags: 1 = relu, 2 = bf16 output
template <int BN>
__global__ __launch_bounds__(256) void gemm_bf16(const uint16_t* __restrict__ A,
                                                 const uint16_t* __restrict__ Bt,
                                                 void* __restrict__ C,
                                                 const float* __restrict__ bias,
                                                 const float* __restrict__ resid,
                                                 int M, int N, int K, int lda,
                                                 int ldb, int flags) {
  constexpr int NJ = BN / 32;  // j-frags per wave
  __shared__ __align__(16) uint16_t As[128 * 64];
  __shared__ __align__(16) uint16_t Bs[BN * 64];
  const int tid = threadIdx.x;
  const int lane = tid & 63, w = tid >> 6;
  const int quad = lane >> 4, lr = lane & 15;
  const int wr = w >> 1, wc = w & 1;

  const int n_tiles = N / BN;
  const int pid = blockIdx.x;
  const int grp = 16 * n_tiles;
  const int gid = pid / grp;
  const int rem = pid - gid * grp;
  const int nt = rem / 16;
  const int mt = gid * 16 + (rem - nt * 16);
  const int bn0 = nt * BN, bm0 = mt * 128;

  f32x4 acc[4][NJ];
#pragma unroll
  for (int i = 0; i < 4; i++)
#pragma unroll
    for (int j = 0; j < NJ; j++) acc[i][j] = f32x4{0.f, 0.f, 0.f, 0.f};

  const int s_row = lane >> 3, s_slot = lane & 7;

  for (int k0 = 0; k0 < K; k0 += 64) {
#pragma unroll
    for (int u = 0; u < 4; u++) {
      const int r = w * 32 + u * 8 + s_row;
      const int cg = s_slot ^ (r & 7);
      GLD_LDS(A + (size_t)(bm0 + r) * lda + k0 + cg * 8, As + (w * 32 + u * 8) * 64);
    }
#pragma unroll
    for (int u = 0; u < NJ; u++) {
      const int r = w * (BN / 4) + u * 8 + s_row;
      const int cg = s_slot ^ (r & 7);
      GLD_LDS(Bt + (size_t)(bn0 + r) * ldb + k0 + cg * 8,
              Bs + (w * (BN / 4) + u * 8) * 64);
    }
    __syncthreads();

#pragma unroll
    for (int ks = 0; ks < 2; ks++) {
      bf16x8 af[4], bfr[NJ];
#pragma unroll
      for (int i = 0; i < 4; i++) {
        const int m = wr * 64 + i * 16 + lr;
        const int slot = (ks * 4 + quad) ^ (m & 7);
        af[i] = *(const bf16x8*)(As + m * 64 + slot * 8);
      }
#pragma unroll
      for (int j = 0; j < NJ; j++) {
        const int n = wc * (BN / 2) + j * 16 + lr;
        const int slot = (ks * 4 + quad) ^ (n & 7);
        bfr[j] = *(const bf16x8*)(Bs + n * 64 + slot * 8);
      }
#pragma unroll
      for (int i = 0; i < 4; i++)
#pragma unroll
        for (int j = 0; j < NJ; j++)
          acc[i][j] =
              __builtin_amdgcn_mfma_f32_16x16x32_bf16(af[i], bfr[j], acc[i][j], 0, 0, 0);
    }
    __syncthreads();
  }

  const int base_m = bm0 + wr * 64 + quad * 4;
  const int base_n = bn0 + wc * (BN / 2) + lr;
#pragma unroll
  for (int i = 0; i < 4; i++) {
#pragma unroll
    for (int j = 0; j < NJ; j++) {
      const int col = base_n + j * 16;
      const float bv = bias ? bias[col] : 0.f;
#pragma unroll
      for (int r = 0; r < 4; r++) {
        const size_t row = base_m + i * 16 + r;
        float v = acc[i][j][r] + bv;
        if (resid) v += resid[row * N + col];
        if (flags & 1) v = fmaxf(v, 0.f);
        if (flags & 2)
          ((uint16_t*)C)[row * N + col] = f2bf(v);
        else
          ((float*)C)[row * N + col] = v;
      }
    }
  }
}

// ---------------- 256x256 8-phase bf16 MFMA GEMM (faithful T3+T4+T5) ----------
// 512 thr = 8 waves (2M x 4N), per-wave out 128x64. BK=64; iteration = 2 K-tiles
// (buf0 = even tile, buf1 = odd tile), 8 phases/iter. Each phase:
//   { ds_read quadrant (4-8 x b128) ; issue ONE half-tile pair (2 gld_lds) ;
//     s_barrier ; setprio(1) 16xMFMA setprio(0) ; [VMW] ; s_barrier }
// Staging spread 2 loads/phase (m196 lever); tile t staged in the 4 phases
// preceding its compute, into the buffer freed by tile t-2 (landing windows
// verified against last-read points). Counted waits ONLY at ph3/ph7 tails:
// VMW(2) with 10 outstanding retires exactly the next K-tile's 8 loads and
// keeps 2 in flight across the boundary (never drains mid-loop; m218 T4).
// Ledger: prologue 10 -> VMW(2) -> 2; +2/phase -> 8; tail +2 = 10 -> VMW(2).
// Peeled last iteration drains with VMW(0) at ph3.
// Accumulation order per acc element: tile asc, ks asc == 2-phase kernel.
// Requires M%256==0, N%256==0, K%128==0, K>=128, grid%8==0.
#define STAGE_PAIR(buf, kt, p)                                                 \
  do {                                                                         \
    const int k0s = (kt) * 64;                                                 \
    if ((p) < 2) {                                                             \
      _Pragma("unroll") for (int u = 0; u < 2; u++) {                          \
        const int r = w * 32 + ((p) * 2 + u) * 8 + s_row;                      \
        const int cg = s_slot ^ (r & 7);                                       \
        GLD_LDS(Bt + (size_t)(bn0 + r) * ldb + k0s + cg * 8,                   \
                &Bs[buf][(w * 32 + ((p) * 2 + u) * 8) * 64]);                  \
      }                                                                        \
    } else {                                                                   \
      const int rb = (w >> 2) * 128 + (w & 3) * 16 + ((p) - 2) * 64;           \
      _Pragma("unroll") for (int u = 0; u < 2; u++) {                          \
        const int r = rb + u * 8 + s_row;                                      \
        const int cg = s_slot ^ (r & 7);                                       \
        GLD_LDS(A + (size_t)(bm0 + r) * lda + k0s + cg * 8,                    \
                &As[buf][(rb + u * 8) * 64]);                                  \
      }                                                                        \
    }                                                                          \
  } while (0)

#define RD_A8Q(dst, ibase, ks, BUF)                                            \
  _Pragma("unroll") for (int i = 0; i < 4; i++) {                              \
    const int m = wr * 128 + ((ibase) + i) * 16 + lr;                          \
    const int slot = ((ks) * 4 + quad) ^ (m & 7);                              \
    dst[i] = *(const bf16x8*)(&As[BUF][m * 64 + slot * 8]);                    \
  }

#define RD_B8Q(dst, ks, BUF)                                                   \
  _Pragma("unroll") for (int j = 0; j < 4; j++) {                              \
    const int n = wc * 64 + j * 16 + lr;                                       \
    const int slot = ((ks) * 4 + quad) ^ (n & 7);                              \
    dst[j] = *(const bf16x8*)(&Bs[BUF][n * 64 + slot * 8]);                    \
  }

#define MFMA16(ibase, aarr)                                                    \
  do {                                                                         \
    __builtin_amdgcn_s_setprio(1);                                             \
    _Pragma("unroll") for (int i = 0; i < 4; i++)                              \
        _Pragma("unroll") for (int j = 0; j < 4; j++) acc[(ibase) + i][j] =    \
        __builtin_amdgcn_mfma_f32_16x16x32_bf16(aarr[i], bb[j],                \
                                                acc[(ibase) + i][j], 0, 0, 0); \
    __builtin_amdgcn_s_setprio(0);                                             \
  } while (0)

#define VMW(n) asm volatile("s_waitcnt vmcnt(" #n ")" ::: "memory")
#define BAR() __builtin_amdgcn_s_barrier()

__global__ __launch_bounds__(512, 2) void gemm_8ph(
    const uint16_t* __restrict__ A, const uint16_t* __restrict__ Bt,
    void* __restrict__ C, const float* __restrict__ bias,
    const float* __restrict__ resid, int M, int N, int K, int lda, int ldb,
    int flags) {
  __shared__ __align__(16) uint16_t As[2][256 * 64];  // 64 KiB
  __shared__ __align__(16) uint16_t Bs[2][256 * 64];  // 64 KiB
  const int tid = threadIdx.x;
  const int lane = tid & 63, w = tid >> 6;
  const int quad = lane >> 4, lr = lane & 15;
  const int wr = w >> 2, wc = w & 3;  // 2 x 4 wave grid; per-wave out 128x64
  const int s_row = lane >> 3, s_slot = lane & 7;

  // bijective XCD swizzle (grid % 8 == 0), then n-fastest raster.
  const int nwg = gridDim.x;
  const int cpx = nwg >> 3;
  const int pid0 = blockIdx.x;
  const int pid = (pid0 & 7) * cpx + (pid0 >> 3);
  const int n_tiles = N >> 8;
  const int mt = pid / n_tiles;
  const int nt = pid - mt * n_tiles;
  const int bm0 = mt * 256, bn0 = nt * 256;

  f32x4 acc[8][4];
#pragma unroll
  for (int i = 0; i < 8; i++)
#pragma unroll
    for (int j = 0; j < 4; j++) acc[i][j] = f32x4{0.f, 0.f, 0.f, 0.f};

  // prologue: tile 0 fully + pair0 of tile 1 (10 outstanding) -> VMW(2)
  STAGE_PAIR(0, 0, 0);
  STAGE_PAIR(0, 0, 1);
  STAGE_PAIR(0, 0, 2);
  STAGE_PAIR(0, 0, 3);
  STAGE_PAIR(1, 1, 0);
  VMW(2);
  BAR();

  const int NIT = K >> 7;  // iterations of 2 K-tiles
  for (int it = 0; it < NIT - 1; ++it) {
    const int v = 2 * it + 1, wt = 2 * it + 2, vn = 2 * it + 3;
    bf16x8 a0[4], a1[4], bb[4];
    // ph0: tile u=2it, q0 (ks0, frags 0-3)
    RD_A8Q(a0, 0, 0, 0);
    RD_B8Q(bb, 0, 0);
    STAGE_PAIR(1, v, 1);
    BAR();
    MFMA16(0, a0);
    BAR();
    // ph1: u q1 (ks0, frags 4-7)
    RD_A8Q(a1, 4, 0, 0);
    STAGE_PAIR(1, v, 2);
    BAR();
    MFMA16(4, a1);
    BAR();
    // ph2: u q2 (ks1, frags 0-3)
    RD_A8Q(a0, 0, 1, 0);
    RD_B8Q(bb, 1, 0);
    STAGE_PAIR(1, v, 3);
    BAR();
    MFMA16(0, a0);
    BAR();
    // ph3: u q3; counted boundary wait (retire v's 8, keep wt-pair0 in flight)
    RD_A8Q(a1, 4, 1, 0);
    STAGE_PAIR(0, wt, 0);
    BAR();
    MFMA16(4, a1);
    VMW(2);
    BAR();
    // ph4: tile v, q0
    RD_A8Q(a0, 0, 0, 1);
    RD_B8Q(bb, 0, 1);
    STAGE_PAIR(0, wt, 1);
    BAR();
    MFMA16(0, a0);
    BAR();
    // ph5: v q1
    RD_A8Q(a1, 4, 0, 1);
    STAGE_PAIR(0, wt, 2);
    BAR();
    MFMA16(4, a1);
    BAR();
    // ph6: v q2
    RD_A8Q(a0, 0, 1, 1);
    RD_B8Q(bb, 1, 1);
    STAGE_PAIR(0, wt, 3);
    BAR();
    MFMA16(0, a0);
    BAR();
    // ph7: v q3; counted boundary wait (retire wt's 8, keep vn-pair0 in flight)
    RD_A8Q(a1, 4, 1, 1);
    STAGE_PAIR(1, vn, 0);
    BAR();
    MFMA16(4, a1);
    VMW(2);
    BAR();
  }
  {  // peeled last iteration: u=NT-2 (buf0), v=NT-1 (buf1); drain at ph3
    const int vL = (K >> 6) - 1;
    bf16x8 a0[4], a1[4], bb[4];
    // ph0
    RD_A8Q(a0, 0, 0, 0);
    RD_B8Q(bb, 0, 0);
    STAGE_PAIR(1, vL, 1);
    BAR();
    MFMA16(0, a0);
    BAR();
    // ph1
    RD_A8Q(a1, 4, 0, 0);
    STAGE_PAIR(1, vL, 2);
    BAR();
    MFMA16(4, a1);
    BAR();
    // ph2
    RD_A8Q(a0, 0, 1, 0);
    RD_B8Q(bb, 1, 0);
    STAGE_PAIR(1, vL, 3);
    BAR();
    MFMA16(0, a0);
    BAR();
    // ph3: drain (no more staging exists)
    RD_A8Q(a1, 4, 1, 0);
    BAR();
    MFMA16(4, a1);
    VMW(0);
    BAR();
    // ph4-7: tile v from buf1, no staging, no waits
    RD_A8Q(a0, 0, 0, 1);
    RD_B8Q(bb, 0, 1);
    BAR();
    MFMA16(0, a0);
    BAR();
    RD_A8Q(a1, 4, 0, 1);
    BAR();
    MFMA16(4, a1);
    BAR();
    RD_A8Q(a0, 0, 1, 1);
    RD_B8Q(bb, 1, 1);
    BAR();
    MFMA16(0, a0);
    BAR();
    RD_A8Q(a1, 4, 1, 1);
    MFMA16(4, a1);
  }

  const int base_m = bm0 + wr * 128 + quad * 4;
  const int base_n = bn0 + wc * 64 + lr;
#pragma unroll
  for (int i = 0; i < 8; i++) {
#pragma unroll
    for (int j = 0; j < 4; j++) {
      const int col = base_n + j * 16;
      const float bv = bias ? bias[col] : 0.f;
#pragma unroll
      for (int r = 0; r < 4; r++) {
        const size_t row = base_m + i * 16 + r;
        float v = acc[i][j][r] + bv;
        if (resid) v += resid[row * N + col];
        if (flags & 1) v = fmaxf(v, 0.f);
        if (flags & 2)
          ((uint16_t*)C)[row * N + col] = f2bf(v);
        else
          ((float*)C)[row * N + col] = v;
      }
    }
  }
}

// ---- V transpose: qkv V-region [B*T][3072] -> vtb [(b*H+h)*64+e][T] bf16 ----
__global__ __launch_bounds__(256) void v_transpose(const uint16_t* __restrict__ qkv,
                                                   uint16_t* __restrict__ vtb) {
  __shared__ __align__(16) uint16_t tile[64 * 72];  // [t-local][e]
  const int tid = threadIdx.x;
  const int t0 = blockIdx.x * 64;
  const int bh = blockIdx.y;
  const int b = bh >> 4, h = bh & 15;
  const uint16_t* src = qkv + (size_t)b * T_ * 3072 + 2048 + h * 64;
#pragma unroll
  for (int u = 0; u < 2; u++) {
    const int uu = tid + u * 256;
    const int r = uu >> 3, c = uu & 7;
    *(int4*)(tile + r * 72 + c * 8) =
        *(const int4*)(src + (size_t)(t0 + r) * 3072 + c * 8);
  }
  __syncthreads();
  uint16_t* dst = vtb + ((size_t)bh * 64) * T_ + t0;
#pragma unroll
  for (int u = 0; u < 2; u++) {
    const int uu = tid + u * 256;
    const int e = uu >> 3, c2 = uu & 7;
    union { uint16_t u16[8]; int4 v; } tmp;
#pragma unroll
    for (int jj = 0; jj < 8; jj++) tmp.u16[jj] = tile[(c2 * 8 + jj) * 72 + e];
    *(int4*)(dst + (size_t)e * T_ + c2 * 8) = tmp.v;
  }
}

// ---- per-stage compute for one q-tile (S^T MFMA + static-max softmax + PV) ----
__device__ __forceinline__ void attn_tile_compute(
    const uint16_t* __restrict__ Kb, const uint16_t* __restrict__ Vb,
    uint16_t* __restrict__ Ps, const bf16x8 (&aq)[2][2], f32x4 (&oacc)[2][4],
    float (&l_part)[2], int st, int q0, int w, int quad, int lr) {
  const int lr7 = lr & 7;
  const int row_min_w = q0 + w * 32;

  // S^T = K @ Q^T : frag rows = s (4 sf-frags), cols = m (2 i-frags)
  f32x4 sa[2][4];
#pragma unroll
  for (int i = 0; i < 2; i++)
#pragma unroll
    for (int sf = 0; sf < 4; sf++) sa[i][sf] = f32x4{0.f, 0.f, 0.f, 0.f};
#pragma unroll
  for (int ks = 0; ks < 2; ks++) {
    bf16x8 ak[4];
#pragma unroll
    for (int sf = 0; sf < 4; sf++) {
      const int slot = (ks * 4 + quad) ^ lr7;
      ak[sf] = *(const bf16x8*)(Kb + (sf * 16 + lr) * 64 + slot * 8);
    }
#pragma unroll
    for (int i = 0; i < 2; i++)
#pragma unroll
      for (int sf = 0; sf < 4; sf++)
        sa[i][sf] =
            __builtin_amdgcn_mfma_f32_16x16x32_bf16(ak[sf], aq[i][ks], sa[i][sf], 0, 0, 0);
  }

  // p = exp2(s*log2e/8 - 20*log2e); mask only on the diagonal stage
  const bool diag = (st * 64 + 63 > row_min_w);
  if (diag) {
#pragma unroll
    for (int i = 0; i < 2; i++) {
      const int mrow = q0 + w * 32 + i * 16 + lr;
#pragma unroll
      for (int sf = 0; sf < 4; sf++) {
        const int s0 = st * 64 + sf * 16 + quad * 4;
        float p[4];
#pragma unroll
        for (int r = 0; r < 4; r++) {
          float sv = sa[i][sf][r];
          if (s0 + r > mrow) sv = -1e30f;
          p[r] = exp2f(fmaf(sv, 0.18033688f, -28.8539008f));
          l_part[i] += p[r];
        }
        ushort4 pk;
        pk.x = f2bf(p[0]);
        pk.y = f2bf(p[1]);
        pk.z = f2bf(p[2]);
        pk.w = f2bf(p[3]);
        *(ushort4*)(Ps + (size_t)(w * 32 + i * 16 + lr) * 72 + sf * 16 + quad * 4) = pk;
      }
    }
  } else {
#pragma unroll
    for (int i = 0; i < 2; i++) {
#pragma unroll
      for (int sf = 0; sf < 4; sf++) {
        float p[4];
#pragma unroll
        for (int r = 0; r < 4; r++) {
          p[r] = exp2f(fmaf(sa[i][sf][r], 0.18033688f, -28.8539008f));
          l_part[i] += p[r];
        }
        ushort4 pk;
        pk.x = f2bf(p[0]);
        pk.y = f2bf(p[1]);
        pk.z = f2bf(p[2]);
        pk.w = f2bf(p[3]);
        *(ushort4*)(Ps + (size_t)(w * 32 + i * 16 + lr) * 72 + sf * 16 + quad * 4) = pk;
      }
    }
  }

  // O += P @ V (per-wave LDS region, same-wave write->read)
#pragma unroll
  for (int ks = 0; ks < 2; ks++) {
    bf16x8 ap[2], bv[4];
#pragma unroll
    for (int i = 0; i < 2; i++)
      ap[i] = *(const bf16x8*)(Ps + (size_t)(w * 32 + i * 16 + lr) * 72 + ks * 32 +
                               quad * 8);
#pragma unroll
    for (int j = 0; j < 4; j++) {
      const int slot = (ks * 4 + quad) ^ lr7;
      bv[j] = *(const bf16x8*)(Vb + (j * 16 + lr) * 64 + slot * 8);
    }
#pragma unroll
    for (int i = 0; i < 2; i++)
#pragma unroll
      for (int j = 0; j < 4; j++)
        oacc[i][j] =
            __builtin_amdgcn_mfma_f32_16x16x32_bf16(ap[i], bv[j], oacc[i][j], 0, 0, 0);
  }
}

// ---------------- MFMA flash attention: paired q-tiles + XCD-local K/V ----------
__global__ __launch_bounds__(256) void attn_mfma(const uint16_t* __restrict__ qkv,
                                                 const uint16_t* __restrict__ vtb,
                                                 uint16_t* __restrict__ ctx) {
  __shared__ __align__(16) uint16_t Ks[64 * 64];   // [s][d] swizzled chunks
  __shared__ __align__(16) uint16_t Vt[64 * 64];   // [d][s] swizzled chunks
  __shared__ __align__(16) uint16_t Ps[128 * 72];  // [m][s] plain, padded
  const int tid = threadIdx.x;
  const int lane = tid & 63, w = tid >> 6;
  const int quad = lane >> 4, lr = lane & 15;
  const int pid = blockIdx.x;
  const int bh = pid & 63;         // same XCD for all i of this (b,h)
  const int i_pair = pid >> 6;     // 0..7
  const int b = bh >> 4, h = bh & 15;
  const uint16_t* base = qkv + (size_t)b * T_ * 3072 + h * 64;
  const uint16_t* vbase = vtb + ((size_t)bh * 64) * T_;
  const int s_row = lane >> 3, s_slot = lane & 7;

  const int tqA = i_pair, tqB = 15 - i_pair;
  const int q0A = tqA * 128, q0B = tqB * 128;
  const int nstgA = 2 * tqA + 2, nstgB = 2 * tqB + 2;
  const int nstg = (nstgA > nstgB) ? nstgA : nstgB;

  bf16x8 aqA[2][2], aqB[2][2];
#pragma unroll
  for (int i = 0; i < 2; i++)
#pragma unroll
    for (int ks = 0; ks < 2; ks++) {
      aqA[i][ks] = *(const bf16x8*)(base + (size_t)(q0A + w * 32 + i * 16 + lr) * 3072 +
                                    ks * 32 + quad * 8);
      aqB[i][ks] = *(const bf16x8*)(base + (size_t)(q0B + w * 32 + i * 16 + lr) * 3072 +
                                    ks * 32 + quad * 8);
    }

  f32x4 oaccA[2][4], oaccB[2][4];
#pragma unroll
  for (int i = 0; i < 2; i++)
#pragma unroll
    for (int j = 0; j < 4; j++) {
      oaccA[i][j] = f32x4{0.f, 0.f, 0.f, 0.f};
      oaccB[i][j] = f32x4{0.f, 0.f, 0.f, 0.f};
    }
  float lA[2] = {0.f, 0.f}, lB[2] = {0.f, 0.f};

  const int row_maxA = q0A + w * 32 + 31;
  const int row_maxB = q0B + w * 32 + 31;

  for (int st = 0; st < nstg; st++) {
    __syncthreads();  // prior stage's LDS reads complete
#pragma unroll
    for (int u = 0; u < 2; u++) {
      const int r = w * 16 + u * 8 + s_row;
      const int cg = s_slot ^ (r & 7);
      GLD_LDS(base + 1024 + (size_t)(st * 64 + r) * 3072 + cg * 8,
              Ks + (w * 16 + u * 8) * 64);
      GLD_LDS(vbase + (size_t)r * T_ + st * 64 + cg * 8, Vt + (w * 16 + u * 8) * 64);
    }
    __syncthreads();

    if (st < nstgA && st * 64 <= row_maxA)
      attn_tile_compute(Ks, Vt, Ps, aqA, oaccA, lA, st, q0A, w, quad, lr);
    if (st < nstgB && st * 64 <= row_maxB)
      attn_tile_compute(Ks, Vt, Ps, aqB, oaccB, lB, st, q0B, w, quad, lr);
  }

  // epilogue: reduce l, normalize, store both q-tiles
#pragma unroll
  for (int half = 0; half < 2; half++) {
    const int q0 = half ? q0B : q0A;
    f32x4(&oacc)[2][4] = half ? oaccB : oaccA;
    float* l_part = half ? lB : lA;
    float linv[2];
#pragma unroll
    for (int i = 0; i < 2; i++) {
      float l = l_part[i];
      l += __shfl_xor(l, 16, 64);
      l += __shfl_xor(l, 32, 64);
      linv[i] = 1.f / l;
    }
    uint16_t* ob =
        ctx + ((size_t)b * T_ + q0 + w * 32 + quad * 4) * D_ + h * 64 + lr;
#pragma unroll
    for (int i = 0; i < 2; i++)
#pragma unroll
      for (int r = 0; r < 4; r++) {
        const float inv = __shfl(linv[i], quad * 4 + r, 64);
#pragma unroll
        for (int j = 0; j < 4; j++)
          ob[(size_t)(i * 16 + r) * D_ + j * 16] = f2bf(oacc[i][j][r] * inv);
      }
  }
}

extern "C" void kernel_launch(void* const* d_in, const int* in_sizes, int n_in,
                              void* d_out, int out_size, void* d_ws, size_t ws_size,
                              hipStream_t stream) {
  const float* x = (const float*)d_in[0];
  const float* Wq = (const float*)d_in[1];
  const float* Wk = (const float*)d_in[2];
  const float* Wv = (const float*)d_in[3];
  const float* Wo = (const float*)d_in[4];
  const float* bo = (const float*)d_in[5];
  const float* W1 = (const float*)d_in[6];
  const float* b1 = (const float*)d_in[7];
  const float* W2 = (const float*)d_in[8];
  const float* b2 = (const float*)d_in[9];
  const float* g1 = (const float*)d_in[10];
  const float* be1 = (const float*)d_in[11];
  const float* g2 = (const float*)d_in[12];
  const float* be2 = (const float*)d_in[13];
  float* out = (float*)d_out;

  const size_t MB = 1024ull * 1024ull;
  if (ws_size < 200 * MB) return;
  char* ws = (char*)d_ws;
  uint16_t* hbuf = (uint16_t*)(ws + 0 * MB);    // 16 MB (LN out, reused)
  uint16_t* wqkvt = (uint16_t*)(ws + 16 * MB);  // 6 MB  [3072][1024]
  uint16_t* wot = (uint16_t*)(ws + 22 * MB);    // 2 MB  [1024][1024]
  uint16_t* w1t = (uint16_t*)(ws + 24 * MB);    // 8 MB  [4096][1024]
  uint16_t* w2t = (uint16_t*)(ws + 32 * MB);    // 8 MB  [1024][4096]
  float* x1 = (float*)(ws + 40 * MB);           // 32 MB
  uint16_t* qkvb = (uint16_t*)(ws + 72 * MB);   // 48 MB [8192][3072]
  uint16_t* ctxb = (uint16_t*)(ws + 120 * MB);  // 16 MB [8192][1024]
  uint16_t* vtb = (uint16_t*)(ws + 136 * MB);   // 16 MB (dead before ffb written)
  uint16_t* ffb = (uint16_t*)(ws + 136 * MB);   // 64 MB [8192][4096]

  prep_ln<<<20480, 256, 0, stream>>>(x, g1, be1, hbuf, Wq, Wk, Wv, Wo, W1, W2,
                                     wqkvt, wot, w1t, w2t);
  // QKV: M=8192, N=3072, K=1024 -> 2-phase 128^2 (proven at K=1024)
  gemm_bf16<128><<<64 * 24, 256, 0, stream>>>(hbuf, wqkvt, qkvb, nullptr, nullptr,
                                              M_, 3 * D_, D_, D_, D_, 2);
  v_transpose<<<dim3(T_ / 64, B_ * H_), 256, 0, stream>>>(qkvb, vtb);
  attn_mfma<<<512, 256, 0, stream>>>(qkvb, vtb, ctxb);
  // Wo: r0 config (BN=64)
  gemm_bf16<64><<<64 * 16, 256, 0, stream>>>(ctxb, wot, x1, bo, x, M_, D_, D_, D_,
                                             D_, 0);
  ln_bf16<<<M_, 256, 0, stream>>>(x1, g2, be2, hbuf);
  // FFN1: M=8192, N=4096, K=1024 -> 8-phase 256^2 (512 blocks = 2 clean rounds)
  gemm_8ph<<<(M_ / 256) * (DFF_ / 256), 512, 0, stream>>>(
      hbuf, w1t, ffb, b1, nullptr, M_, DFF_, D_, D_, D_, 1 | 2);
  // FFN2: r0 config (BN=64)
  gemm_bf16<64><<<64 * 16, 256, 0, stream>>>(ffb, w2t, out, b2, x1, M_, D_, DFF_,
                                             DFF_, DFF_, 0);
}